// Round 15
// baseline (167.117 us; speedup 1.0000x reference)
//
#include <hip/hip_runtime.h>
#include <hip/hip_bf16.h>
#include <math.h>
#include <limits.h>

// Problem dims
constexpr int NB    = 4096;   // batch
constexpr int ROWS2 = NB * 12;            // 49152 rows for the 2->100->100->2 MLPs
constexpr int GA_BLOCKS = ROWS2 / 128;    // 384 (128 rows/block, vector path)
constexpr int GS_BLOCKS = ROWS2 / 64;     // 768 (64 rows/block, MFMA path)
constexpr int GSC_BLOCKS = NB / 64;       // 64 (64 rows/block, MFMA path)
constexpr int TBL_CAP = 64;               // lattice slots per channel (fixed range)
constexpr int KBASE   = -32;              // fixed kmin for all channels

// workspace layout (float offsets)
constexpr size_t WS_Y1    = 0;              // NB*24
constexpr size_t WS_YHAT  = 98304;          // NB*24
constexpr size_t WS_YHAT1 = 196608;         // NB*24
constexpr size_t WS_YM    = 294912;         // 24
constexpr size_t WS_U2T   = 294936;         // 24*256 (transposed: [c][m])
constexpr size_t WS_EB    = 301080;         // 24*58 precomputed prior params
constexpr size_t WS_PART  = 302472;         // per-block mean partials
constexpr size_t WS_W1T   = 320904;         // 2 x [100][128] transposed w1 (ga,gac)
constexpr size_t WS_W1BFGS  = 346504;       // gs  w1 bf16 [112][128] (3584 f)
constexpr size_t WS_W1BFGSC = 350088;       // gsc w1 bf16 [128][128] (8192 f)
constexpr size_t WS_W2BFGSC = 358280;       // gsc w2 bf16 [32][128]  (2048 f)
constexpr size_t WS_TBL   = 360328;         // 24*64*256 table of log(pdf+1e-9)
constexpr size_t WS_END   = WS_TBL + 24 * TBL_CAP * 256;   // 753544 floats (~3.0 MB)

constexpr float STEP_ODD = 0.8660254037844386f;   // sqrt(3)/2
constexpr float INV_ODD  = 1.1547005383792517f;   // 2/sqrt(3)

typedef __attribute__((ext_vector_type(8))) short bf16x8;
typedef __attribute__((ext_vector_type(4))) float f32x4;

__device__ __forceinline__ float lrelu(float x) { return x >= 0.f ? x : 0.01f * x; }
__device__ __forceinline__ float rcp_fast(float x) { return __builtin_amdgcn_rcpf(x); }

__device__ __forceinline__ unsigned short f2bf(float f) {   // RNE f32 -> bf16
    unsigned b = __float_as_uint(f);
    b += 0x7FFFu + ((b >> 16) & 1u);
    return (unsigned short)(b >> 16);
}

__device__ __forceinline__ float tanh_fast(float x) {
    float xx = fminf(fmaxf(x, -15.f), 15.f);
    float e = __expf(xx + xx);
    return fmaf(-2.f, rcp_fast(e + 1.f), 1.f);
}
__device__ __forceinline__ float splus(float x) {
    return fmaxf(x, 0.f) + __logf(1.f + __expf(-fabsf(x)));
}
__device__ __forceinline__ float splus_precise(float x) {
    return fmaxf(x, 0.f) + log1pf(expf(-fabsf(x)));
}

__device__ __forceinline__ void fma4(float4& a, float h, const float4& w) {
    a.x = fmaf(h, w.x, a.x); a.y = fmaf(h, w.y, a.y);
    a.z = fmaf(h, w.z, a.z); a.w = fmaf(h, w.w, a.w);
}

// exact A2 hex lattice nearest-point quantizer; matches jnp.round (rint = RNE)
__device__ __forceinline__ void hexq(float p0, float p1, float& q0, float& q1) {
    const float S3 = 1.7320508075688772f;
    const float H3 = 0.8660254037844386f;
    float c00 = rintf(p0);
    float c01 = rintf(p1 / S3) * S3;
    float c10 = rintf(p0 - 0.5f) + 0.5f;
    float c11 = rintf((p1 - H3) / S3) * S3 + H3;
    float d0 = (p0 - c00) * (p0 - c00) + (p1 - c01) * (p1 - c01);
    float d1 = (p0 - c10) * (p0 - c10) + (p1 - c11) * (p1 - c11);
    bool take0 = d0 <= d1;
    q0 = take0 ? c00 : c10;
    q1 = take0 ? c01 : c11;
}

// per-channel prior chain: log(pdf + 1e-9) at point p, params P (58 floats)
__device__ __forceinline__ float logpdf_ch(const float* __restrict__ P, float p) {
    float w00 = P[0], w01 = P[1], w02 = P[2];
    float z0 = fmaf(w00, p, P[3]);
    float z1 = fmaf(w01, p, P[4]);
    float z2 = fmaf(w02, p, P[5]);
    float a0 = P[6], a1 = P[7], a2 = P[8];
    float e0 = tanh_fast(z0), e1 = tanh_fast(z1), e2 = tanh_fast(z2);
    float h0 = fmaf(a0, e0, z0), h1 = fmaf(a1, e1, z1), h2 = fmaf(a2, e2, z2);
    float t0 = w00 * fmaf(a0, fmaf(-e0, e0, 1.f), 1.f);
    float t1 = w01 * fmaf(a1, fmaf(-e1, e1, 1.f), 1.f);
    float t2 = w02 * fmaf(a2, fmaf(-e2, e2, 1.f), 1.f);

#define EB_LAYER(O)                                                            \
    {                                                                          \
        float z0n = fmaf(P[O+0], h0, fmaf(P[O+1], h1, fmaf(P[O+2], h2, P[O+9])));  \
        float z1n = fmaf(P[O+3], h0, fmaf(P[O+4], h1, fmaf(P[O+5], h2, P[O+10]))); \
        float z2n = fmaf(P[O+6], h0, fmaf(P[O+7], h1, fmaf(P[O+8], h2, P[O+11]))); \
        float s0 = fmaf(P[O+0], t0, fmaf(P[O+1], t1, P[O+2] * t2));            \
        float s1 = fmaf(P[O+3], t0, fmaf(P[O+4], t1, P[O+5] * t2));            \
        float s2 = fmaf(P[O+6], t0, fmaf(P[O+7], t1, P[O+8] * t2));            \
        float g0 = P[O+12], g1 = P[O+13], g2 = P[O+14];                        \
        float q0 = tanh_fast(z0n), q1 = tanh_fast(z1n), q2 = tanh_fast(z2n);   \
        h0 = fmaf(g0, q0, z0n); h1 = fmaf(g1, q1, z1n); h2 = fmaf(g2, q2, z2n); \
        t0 = s0 * fmaf(g0, fmaf(-q0, q0, 1.f), 1.f);                           \
        t1 = s1 * fmaf(g1, fmaf(-q1, q1, 1.f), 1.f);                           \
        t2 = s2 * fmaf(g2, fmaf(-q2, q2, 1.f), 1.f);                           \
    }
    EB_LAYER(9)
    EB_LAYER(24)
    EB_LAYER(39)
#undef EB_LAYER

    float L = fmaf(P[54], h0, fmaf(P[55], h1, fmaf(P[56], h2, P[57])));
    float T = fmaf(P[54], t0, fmaf(P[55], t1, P[56] * t2));
    float Lc = fminf(fmaxf(L, -30.f), 30.f);
    float sg = rcp_fast(1.f + __expf(-Lc));
    float pdf = sg * (1.f - sg) * T;
    return __logf(pdf + 1e-9f);
}

// ---------------------------------------------------------------------------
// K0: block 0: prior params + u2^T.
//     blocks 1..100:   transpose ga/gac w1 into [100][128] zero-padded f32.
//     blocks 101..156: gs  w1 -> bf16 [112][128] zero-padded.
//     blocks 157..220: gsc w1 -> bf16 [128][128] zero-padded.
//     blocks 221..236: gsc w2 -> bf16 [32][128]  zero-padded.
// ---------------------------------------------------------------------------
__global__ __launch_bounds__(256) void k_prep(
    const float* __restrict__ H0p, const float* __restrict__ H1p,
    const float* __restrict__ H2p, const float* __restrict__ H3p,
    const float* __restrict__ H4p,
    const float* __restrict__ b0p, const float* __restrict__ b1p,
    const float* __restrict__ b2p, const float* __restrict__ b3p,
    const float* __restrict__ b4p,
    const float* __restrict__ a0p, const float* __restrict__ a1p,
    const float* __restrict__ a2p, const float* __restrict__ a3p,
    const float* __restrict__ u,
    const float* __restrict__ w1ga, const float* __restrict__ w1gac,
    const float* __restrict__ w1gs, const float* __restrict__ w1gsc,
    const float* __restrict__ w2gsc,
    float* __restrict__ eb, float* __restrict__ u2t,
    float* __restrict__ w1t, float* __restrict__ w1bfGS,
    float* __restrict__ w1bfGSC, float* __restrict__ w2bfGSC)
{
    int tid = threadIdx.x;
    if (blockIdx.x > 0) {
        int t = blockIdx.x - 1;
        if (t < 100) {
            int m = t / 50;
            int o = (t % 50) * 256 + tid;       // 0..12799
            int k = o >> 7, i = o & 127;
            const float* src = (m == 0) ? w1ga : w1gac;
            w1t[m * 12800 + o] = (i < 100) ? src[i * 100 + k] : 0.f;
        } else if (t < 156) {
            int o = (t - 100) * 256 + tid;      // 0..14335
            int i = o >> 7, k = o & 127;
            float v = (i < 100 && k < 100) ? w1gs[i * 100 + k] : 0.f;
            ((unsigned short*)w1bfGS)[o] = f2bf(v);
        } else if (t < 220) {
            int o = (t - 156) * 256 + tid;      // 0..16383
            int i = o >> 7, k = o & 127;
            float v = (i < 100 && k < 100) ? w1gsc[i * 100 + k] : 0.f;
            ((unsigned short*)w1bfGSC)[o] = f2bf(v);
        } else {
            int o = (t - 220) * 256 + tid;      // 0..4095
            int c = o >> 7, k = o & 127;
            float v = (c < 24 && k < 100) ? w2gsc[c * 100 + k] : 0.f;
            ((unsigned short*)w2bfGSC)[o] = f2bf(v);
        }
        return;
    }
    if (tid < 24) {
        int c = tid;
        float* P = eb + c * 58;
        for (int j = 0; j < 3; ++j) P[j]      = splus_precise(H0p[c*3+j]);
        for (int j = 0; j < 3; ++j) P[3+j]    = b0p[c*3+j];
        for (int j = 0; j < 3; ++j) P[6+j]    = tanhf(a0p[c*3+j]);
        for (int j = 0; j < 9; ++j) P[9+j]    = splus_precise(H1p[c*9+j]);
        for (int j = 0; j < 3; ++j) P[18+j]   = b1p[c*3+j];
        for (int j = 0; j < 3; ++j) P[21+j]   = tanhf(a1p[c*3+j]);
        for (int j = 0; j < 9; ++j) P[24+j]   = splus_precise(H2p[c*9+j]);
        for (int j = 0; j < 3; ++j) P[33+j]   = b2p[c*3+j];
        for (int j = 0; j < 3; ++j) P[36+j]   = tanhf(a2p[c*3+j]);
        for (int j = 0; j < 9; ++j) P[39+j]   = splus_precise(H3p[c*9+j]);
        for (int j = 0; j < 3; ++j) P[48+j]   = b3p[c*3+j];
        for (int j = 0; j < 3; ++j) P[51+j]   = tanhf(a3p[c*3+j]);
        for (int j = 0; j < 3; ++j) P[54+j]   = splus_precise(H4p[c*3+j]);
        P[57] = b4p[c];
    }
    int m = tid;
    if (m < 256) {
        for (int j = 0; j < 12; ++j) {
            float a  = u[m*24 + 2*j];
            float bb = u[m*24 + 2*j + 1];
            float p0 = fmaf(0.5f, bb, a);
            float p1 = 0.8660254037844386f * bb;
            float q0, q1; hexq(p0, p1, q0, q1);
            u2t[(2*j)   * 256 + m] = p0 - q0;
            u2t[(2*j+1) * 256 + m] = p1 - q1;
        }
    }
}

// ---------------------------------------------------------------------------
// gemm2 body v2 (vector f32, ga path which feeds hexq): 128 rows/block.
// ---------------------------------------------------------------------------
template <int MEAN>
__device__ __forceinline__ void gemm2_body(
    int bid,
    const float* __restrict__ in,
    const float* __restrict__ w0, const float* __restrict__ b0,
    const float* __restrict__ w1t,
    const float* __restrict__ b1, const float* __restrict__ w2,
    const float* __restrict__ b2,
    float* __restrict__ out, float* __restrict__ partial)
{
    __shared__ alignas(16) float shT[100 * 128];  // h0T [k][row]; reused as red
    __shared__ float S[128][2];

    int tid = threadIdx.x;
    int row0 = bid * 128;

    for (int e = tid; e < 12800; e += 256) {
        int j = e >> 7, row = e & 127;
        float2 xv = ((const float2*)in)[row0 + row];
        shT[j * 128 + row] =
            lrelu(fmaf(w0[2*j], xv.x, fmaf(w0[2*j+1], xv.y, b0[j])));
    }

    int rg = tid >> 4;        // rows 8rg..8rg+7
    int cg = tid & 15;        // cols 8cg..8cg+7 (of 128)
    __syncthreads();

    float4 acc0[8], acc1[8];
    float4 zero4 = make_float4(0.f, 0.f, 0.f, 0.f);
#pragma unroll
    for (int r = 0; r < 8; ++r) { acc0[r] = zero4; acc1[r] = zero4; }

    const float4* wg = (const float4*)w1t + cg * 2;
    const float4* hp = (const float4*)shT + rg * 2;
    float4 wa0 = wg[0],  wa1 = wg[1];
    float4 wb0 = wg[32], wb1 = wg[33];
#pragma unroll 2
    for (int k = 0; k < 100; ++k) {
        float4 wn0 = wg[(k + 2) * 32];
        float4 wn1 = wg[(k + 2) * 32 + 1];
        float4 ha = hp[k * 32];
        float4 hb = hp[k * 32 + 1];
        fma4(acc0[0], ha.x, wa0); fma4(acc1[0], ha.x, wa1);
        fma4(acc0[1], ha.y, wa0); fma4(acc1[1], ha.y, wa1);
        fma4(acc0[2], ha.z, wa0); fma4(acc1[2], ha.z, wa1);
        fma4(acc0[3], ha.w, wa0); fma4(acc1[3], ha.w, wa1);
        fma4(acc0[4], hb.x, wa0); fma4(acc1[4], hb.x, wa1);
        fma4(acc0[5], hb.y, wa0); fma4(acc1[5], hb.y, wa1);
        fma4(acc0[6], hb.z, wa0); fma4(acc1[6], hb.z, wa1);
        fma4(acc0[7], hb.w, wa0); fma4(acc1[7], hb.w, wa1);
        wa0 = wb0; wa1 = wb1; wb0 = wn0; wb1 = wn1;
    }
    __syncthreads();

    float b1v[8], w20v[8], w21v[8];
    int c0 = cg * 8;
#pragma unroll
    for (int e = 0; e < 8; ++e) {
        int c = c0 + e;
        bool v = (c < 100);
        b1v[e]  = v ? b1[c] : 0.f;
        w20v[e] = v ? w2[c] : 0.f;
        w21v[e] = v ? w2[100 + c] : 0.f;
    }
    float* red = shT;         // [128][2][16]
#pragma unroll
    for (int r = 0; r < 8; ++r) {
        float a0 = lrelu(acc0[r].x + b1v[0]);
        float a1 = lrelu(acc0[r].y + b1v[1]);
        float a2 = lrelu(acc0[r].z + b1v[2]);
        float a3 = lrelu(acc0[r].w + b1v[3]);
        float a4 = lrelu(acc1[r].x + b1v[4]);
        float a5 = lrelu(acc1[r].y + b1v[5]);
        float a6 = lrelu(acc1[r].z + b1v[6]);
        float a7 = lrelu(acc1[r].w + b1v[7]);
        float y0 = a0*w20v[0] + a1*w20v[1] + a2*w20v[2] + a3*w20v[3]
                 + a4*w20v[4] + a5*w20v[5] + a6*w20v[6] + a7*w20v[7];
        float y1 = a0*w21v[0] + a1*w21v[1] + a2*w21v[2] + a3*w21v[3]
                 + a4*w21v[4] + a5*w21v[5] + a6*w21v[6] + a7*w21v[7];
        int row = rg * 8 + r;
        red[(row * 2) * 16 + cg]     = y0;
        red[(row * 2 + 1) * 16 + cg] = y1;
    }
    __syncthreads();
    {
        int row = tid >> 1, p = tid & 1;
        const float4* rp = (const float4*)&red[(row * 2 + p) * 16];
        float4 v0 = rp[0], v1 = rp[1], v2 = rp[2], v3 = rp[3];
        float s = ((v0.x + v0.y) + (v0.z + v0.w))
                + ((v1.x + v1.y) + (v1.z + v1.w))
                + ((v2.x + v2.y) + (v2.z + v2.w))
                + ((v3.x + v3.y) + (v3.z + v3.w));
        float y = s + b2[p];
        out[(row0 + row) * 2 + p] = y;
        if (MEAN) S[row][p] = y;
    }
    if (MEAN) {
        __syncthreads();
        if (tid < 24) {
            int j = tid >> 1, par = tid & 1;
            int base = row0 % 12;
            int k0 = (j - base + 144) % 12;
            float s = 0.f;
            for (int k = k0; k < 128; k += 12) s += S[k][par];
            partial[bid * 24 + tid] = s;
        }
    }
}

// ---------------------------------------------------------------------------
// gs MFMA body (validated in R14): 64 rows/block, 4 waves x 16-row M-tiles.
// ---------------------------------------------------------------------------
__device__ __forceinline__ void gs_mfma_body(
    int bid,
    const float* __restrict__ in,
    const float* __restrict__ w0, const float* __restrict__ b0,
    const float* __restrict__ w1bf,
    const float* __restrict__ b1, const float* __restrict__ w2,
    const float* __restrict__ b2,
    float* __restrict__ out)
{
    int tid = threadIdx.x;
    int lane = tid & 63, wv = tid >> 6;
    int rsel = lane & 15;
    int kgrp = lane >> 4;
    int row0w = bid * 64 + wv * 16;

    float2 xv = ((const float2*)in)[row0w + rsel];

    bf16x8 afr[4];
#pragma unroll
    for (int kb = 0; kb < 4; ++kb) {
#pragma unroll
        for (int j8 = 0; j8 < 8; ++j8) {
            int j = kb * 32 + kgrp * 8 + j8;
            float h = 0.f;
            if (j < 100)
                h = lrelu(fmaf(w0[2*j], xv.x, fmaf(w0[2*j+1], xv.y, b0[j])));
            afr[kb][j8] = (short)f2bf(h);
        }
    }

    const unsigned short* w1u = (const unsigned short*)w1bf;
    f32x4 acc[7];
#pragma unroll
    for (int n = 0; n < 7; ++n) acc[n] = (f32x4){0.f, 0.f, 0.f, 0.f};
#pragma unroll
    for (int kb = 0; kb < 4; ++kb) {
#pragma unroll
        for (int n = 0; n < 7; ++n) {
            bf16x8 bfr = *(const bf16x8*)(w1u + (n * 16 + rsel) * 128
                                              + kb * 32 + kgrp * 8);
            acc[n] = __builtin_amdgcn_mfma_f32_16x16x32_bf16(afr[kb], bfr,
                                                             acc[n], 0, 0, 0);
        }
    }

    float py0[4] = {0.f, 0.f, 0.f, 0.f}, py1[4] = {0.f, 0.f, 0.f, 0.f};
#pragma unroll
    for (int n = 0; n < 7; ++n) {
        int i = n * 16 + rsel;
        bool v = (i < 100);
        float b1v = v ? b1[i] : 0.f;
        float w20 = v ? w2[i] : 0.f;
        float w21 = v ? w2[100 + i] : 0.f;
#pragma unroll
        for (int r = 0; r < 4; ++r) {
            float a = lrelu(acc[n][r] + b1v);
            py0[r] = fmaf(a, w20, py0[r]);
            py1[r] = fmaf(a, w21, py1[r]);
        }
    }
#pragma unroll
    for (int r = 0; r < 4; ++r) {
#pragma unroll
        for (int off = 1; off < 16; off <<= 1) {
            py0[r] += __shfl_xor(py0[r], off);
            py1[r] += __shfl_xor(py1[r], off);
        }
    }
    if (rsel == 0) {
#pragma unroll
        for (int r = 0; r < 4; ++r) {
            int row = row0w + kgrp * 4 + r;
            out[row * 2]     = py0[r] + b2[0];
            out[row * 2 + 1] = py1[r] + b2[1];
        }
    }
}

// ---------------------------------------------------------------------------
// gsc MFMA body: yhat (4096x24) -> 100 (splus) -> 100 (splus) -> 24, +ym.
// Post-quantization => bf16-safe. 64 rows/block, 4 waves x 16-row M-tiles.
// Layer-0 (K=24) f32 direct into A-frags; layer-1 = 8Nx4K MFMA vs bf16 w1
// [128][128]; splus -> per-wave LDS transpose -> layer-2 = 2Nx4K MFMA vs
// bf16 w2 [32][128]; +ym; store yhat1. All pads zero => exact zeros.
// ---------------------------------------------------------------------------
__device__ __forceinline__ void gsc_mfma_body(
    int bid,
    const float* __restrict__ yhat,
    const float* __restrict__ w0,
    const float* __restrict__ w1bfC, const float* __restrict__ w2bfC,
    const float* __restrict__ ymg, float* __restrict__ yhat1,
    float* __restrict__ h1L /* LDS [4][128][16] */)
{
    int tid = threadIdx.x;
    int lane = tid & 63, wv = tid >> 6;
    int rsel = lane & 15;
    int kgrp = lane >> 4;
    int row0w = bid * 64 + wv * 16;

    float xr[24];
    const float4* xp = (const float4*)(yhat + (row0w + rsel) * 24);
#pragma unroll
    for (int k4 = 0; k4 < 6; ++k4) {
        float4 t = xp[k4];
        xr[4*k4] = t.x; xr[4*k4+1] = t.y; xr[4*k4+2] = t.z; xr[4*k4+3] = t.w;
    }

    // layer 0 (f32) -> A fragments
    bf16x8 afr[4];
#pragma unroll
    for (int kb = 0; kb < 4; ++kb) {
#pragma unroll
        for (int j8 = 0; j8 < 8; ++j8) {
            int j = kb * 32 + kgrp * 8 + j8;
            float h = 0.f;
            if (j < 100) {
                const float* wr = w0 + j * 24;
                float a = 0.f, b = 0.f;
#pragma unroll
                for (int k = 0; k < 24; k += 2) {
                    a = fmaf(wr[k],     xr[k],     a);
                    b = fmaf(wr[k + 1], xr[k + 1], b);
                }
                h = splus(a + b);
            }
            afr[kb][j8] = (short)f2bf(h);
        }
    }

    // layer 1: 8 N-tiles x 4 K-blocks
    const unsigned short* w1u = (const unsigned short*)w1bfC;
    f32x4 acc[8];
#pragma unroll
    for (int n = 0; n < 8; ++n) acc[n] = (f32x4){0.f, 0.f, 0.f, 0.f};
#pragma unroll
    for (int kb = 0; kb < 4; ++kb) {
#pragma unroll
        for (int n = 0; n < 8; ++n) {
            bf16x8 bfr = *(const bf16x8*)(w1u + (n * 16 + rsel) * 128
                                              + kb * 32 + kgrp * 8);
            acc[n] = __builtin_amdgcn_mfma_f32_16x16x32_bf16(afr[kb], bfr,
                                                             acc[n], 0, 0, 0);
        }
    }

    // splus -> LDS transpose (D: col=rsel -> i = n*16+rsel, row = kgrp*4+r)
    float* hl = h1L + wv * 128 * 16;
#pragma unroll
    for (int n = 0; n < 8; ++n) {
        int i = n * 16 + rsel;
        float v0 = (i < 100) ? splus(acc[n][0]) : 0.f;
        float v1 = (i < 100) ? splus(acc[n][1]) : 0.f;
        float v2 = (i < 100) ? splus(acc[n][2]) : 0.f;
        float v3 = (i < 100) ? splus(acc[n][3]) : 0.f;
        hl[i * 16 + kgrp * 4]     = v0;
        hl[i * 16 + kgrp * 4 + 1] = v1;
        hl[i * 16 + kgrp * 4 + 2] = v2;
        hl[i * 16 + kgrp * 4 + 3] = v3;
    }
    __syncthreads();

    // layer 2 A-frags from LDS (row = rsel, k = kb*32+kgrp*8+j8)
    bf16x8 afr2[4];
#pragma unroll
    for (int kb = 0; kb < 4; ++kb) {
#pragma unroll
        for (int j8 = 0; j8 < 8; ++j8) {
            int i = kb * 32 + kgrp * 8 + j8;
            afr2[kb][j8] = (short)f2bf(hl[i * 16 + rsel]);
        }
    }
    const unsigned short* w2u = (const unsigned short*)w2bfC;
    f32x4 acc2[2];
    acc2[0] = (f32x4){0.f, 0.f, 0.f, 0.f};
    acc2[1] = (f32x4){0.f, 0.f, 0.f, 0.f};
#pragma unroll
    for (int kb = 0; kb < 4; ++kb) {
#pragma unroll
        for (int n = 0; n < 2; ++n) {
            bf16x8 bfr = *(const bf16x8*)(w2u + (n * 16 + rsel) * 128
                                              + kb * 32 + kgrp * 8);
            acc2[n] = __builtin_amdgcn_mfma_f32_16x16x32_bf16(afr2[kb], bfr,
                                                              acc2[n], 0, 0, 0);
        }
    }

#pragma unroll
    for (int n = 0; n < 2; ++n) {
        int c = n * 16 + rsel;
        if (c < 24) {
            float ym = ymg[c];
#pragma unroll
            for (int r = 0; r < 4; ++r)
                yhat1[(row0w + kgrp * 4 + r) * 24 + c] = acc2[n][r] + ym;
        }
    }
}

// ---------------------------------------------------------------------------
// K1: merged dispatch: blocks [0,384) = ga GEMM (y1 + mean partials),
// blocks [384, 384+384) = prior table build (4 v-slots per block).
// ---------------------------------------------------------------------------
__global__ __launch_bounds__(256, 2) void k_ga_table(
    const float* __restrict__ in,
    const float* __restrict__ w0, const float* __restrict__ b0,
    const float* __restrict__ w1t,
    const float* __restrict__ b1, const float* __restrict__ w2,
    const float* __restrict__ b2,
    float* __restrict__ out, float* __restrict__ partial,
    const float* __restrict__ eb, const float* __restrict__ u2t,
    float* __restrict__ tbl)
{
    if (blockIdx.x < (unsigned)GA_BLOCKS) {
        gemm2_body<1>(blockIdx.x, in, w0, b0, w1t, b1, w2, b2, out, partial);
    } else {
        int cv4 = blockIdx.x - GA_BLOCKS;      // 0..383
        int c = cv4 >> 4, vg = (cv4 & 15) * 4;
        int m = threadIdx.x;
        float step = (c & 1) ? STEP_ODD : 0.5f;
        float uv = u2t[c * 256 + m];
        const float* P = eb + c * 58;
#pragma unroll
        for (int dv = 0; dv < 4; ++dv) {
            int v = vg + dv;
            float val = (float)(KBASE + v) * step;
            tbl[(c * TBL_CAP + v) * 256 + m] = logpdf_ch(P, val + uv);
        }
    }
}

// ---------------------------------------------------------------------------
// K2: finish the EMA mean from 384 per-block partials (1 block, sub-us)
// ---------------------------------------------------------------------------
__global__ __launch_bounds__(256) void k_mean_final(
    const float* __restrict__ partial, const float* __restrict__ y_mean,
    float* __restrict__ ym)
{
    int tid = threadIdx.x;
    int c = tid >> 3, s = tid & 7;
    float v = 0.f;
    if (c < 24)
        for (int g = s; g < GA_BLOCKS; g += 8) v += partial[g * 24 + c];
    v += __shfl_xor(v, 1); v += __shfl_xor(v, 2); v += __shfl_xor(v, 4);
    if (c < 24 && s == 0)
        ym[c] = fmaf(0.05f, y_mean[c], 0.95f * (v * (1.0f / NB)));
}

// ---------------------------------------------------------------------------
// K3: gac only (f32, feeds hexq). 8 rows/block, 512 blocks.
// yhat = hexq(gac(y1 - ym)).
// ---------------------------------------------------------------------------
__global__ __launch_bounds__(256, 4) void k_gac(
    const float* __restrict__ y1,
    const float* __restrict__ w0A, const float* __restrict__ w1tA,
    const float* __restrict__ w2A,
    const float* __restrict__ ymg,
    float* __restrict__ yhat)
{
    __shared__ float sw0[2400];
    __shared__ float sw2[2400];
    __shared__ float sX[8 * 25];
    __shared__ float sO[8 * 25];
    __shared__ alignas(16) float h0[100 * 8];   // [j][r]
    __shared__ float h1[100 * 8];               // [i][r]
    __shared__ float symL[24];

    int tid = threadIdx.x;
    int row0 = blockIdx.x * 8;

    if (tid < 24) symL[tid] = ymg[tid];
    for (int t = tid; t < 2400; t += 256) {
        sw0[t] = w0A[t];
        sw2[t] = w2A[t];
    }
    __syncthreads();
    for (int e = tid; e < 192; e += 256) {
        int r = e / 24, c = e - r * 24;
        sX[r * 25 + c] = y1[row0 * 24 + e] - symL[c];
    }
    __syncthreads();

    int ii = tid & 127, rg = tid >> 7;

    // layer 0
    for (int e = tid; e < 800; e += 256) {
        int j = e >> 3, r = e & 7;
        const float* wr = sw0 + j * 24;
        const float* xr = sX + r * 25;
        float a = 0.f, b = 0.f;
#pragma unroll
        for (int k = 0; k < 24; k += 2) {
            a = fmaf(wr[k],     xr[k],     a);
            b = fmaf(wr[k + 1], xr[k + 1], b);
        }
        h0[j * 8 + r] = splus(a + b);
    }
    __syncthreads();

    // layer 1 (w1t column-coalesced from L2)
    {
        float4 a = make_float4(0.f, 0.f, 0.f, 0.f);
        const float* wc = w1tA + ii;
        const float4* h4 = (const float4*)h0 + rg;
#pragma unroll 4
        for (int j = 0; j < 100; ++j) {
            float w = wc[j * 128];
            float4 h = h4[j * 2];
            a.x = fmaf(w, h.x, a.x); a.y = fmaf(w, h.y, a.y);
            a.z = fmaf(w, h.z, a.z); a.w = fmaf(w, h.w, a.w);
        }
        if (ii < 100) {
            h1[ii * 8 + rg * 4]     = splus(a.x);
            h1[ii * 8 + rg * 4 + 1] = splus(a.y);
            h1[ii * 8 + rg * 4 + 2] = splus(a.z);
            h1[ii * 8 + rg * 4 + 3] = splus(a.w);
        }
    }
    __syncthreads();

    // layer 2
    if (tid < 192) {
        int c = tid >> 3, r = tid & 7;
        const float* w2r = sw2 + c * 100;
        float s = 0.f, s2 = 0.f;
#pragma unroll 4
        for (int i = 0; i < 100; i += 2) {
            s  = fmaf(w2r[i],     h1[i * 8 + r],       s);
            s2 = fmaf(w2r[i + 1], h1[(i + 1) * 8 + r], s2);
        }
        sO[r * 25 + c] = s + s2;
    }
    __syncthreads();
    if (tid < 96) {
        int pr = tid >> 3, r = tid & 7;
        float v0 = sO[r * 25 + 2*pr], v1 = sO[r * 25 + 2*pr + 1];
        float q0, q1; hexq(v0, v1, q0, q1);
        yhat[(row0 + r) * 24 + 2*pr]     = q0;
        yhat[(row0 + r) * 24 + 2*pr + 1] = q1;
    }
}

// ---------------------------------------------------------------------------
// K4 (merged): blocks [0,64) = gsc MFMA -> yhat1; blocks [64,64+1024) =
// MC likelihood (4 batch rows/block, unconditional clamped gathers).
// ---------------------------------------------------------------------------
__global__ __launch_bounds__(256, 4) void k_gsc_mc(
    const float* __restrict__ yhat,
    const float* __restrict__ w0C, const float* __restrict__ w1bfC,
    const float* __restrict__ w2bfC, const float* __restrict__ ymg,
    float* __restrict__ yhat1,
    const float* __restrict__ u2t, const float* __restrict__ eb,
    const float* __restrict__ tbl, float* __restrict__ lik)
{
    __shared__ float h1L[4 * 128 * 16];       // 32 KB (gsc branch)
    if (blockIdx.x < (unsigned)GSC_BLOCKS) {
        gsc_mfma_body(blockIdx.x, yhat, w0C, w1bfC, w2bfC, ymg, yhat1, h1L);
        return;
    }
    float* sy = h1L;                          // reuse as [4*24]
    __shared__ float redm[4], reds[4];
    int tid = threadIdx.x;
    int wv = tid >> 6;
    int bg = (blockIdx.x - GSC_BLOCKS) * 4;

    if (tid < 96) sy[tid] = yhat[bg * 24 + tid];
    __syncthreads();

    for (int q = 0; q < 4; ++q) {
        float lp = 0.f;
        unsigned miss = 0;
#pragma unroll
        for (int c = 0; c < 24; ++c) {
            float yv = sy[q * 24 + c];
            float inv = (c & 1) ? INV_ODD : 2.0f;
            int k = (int)rintf(yv * inv);
            int idx = k - KBASE;
            bool ok = (idx >= 0 && idx < TBL_CAP);
            int idq = min(max(idx, 0), TBL_CAP - 1);
            float tv = tbl[(c * TBL_CAP + idq) * 256 + tid];  // unconditional
            lp += ok ? tv : 0.f;
            if (!ok) miss |= (1u << c);
        }
        while (miss) {
            int c = __ffs(miss) - 1;
            miss &= miss - 1;
            lp += logpdf_ch(eb + c * 58, sy[q * 24 + c] + u2t[c * 256 + tid]);
        }

        float m = lp;
#pragma unroll
        for (int off = 1; off < 64; off <<= 1) m = fmaxf(m, __shfl_xor(m, off));
        if ((tid & 63) == 0) redm[wv] = m;
        __syncthreads();
        float mx = fmaxf(fmaxf(redm[0], redm[1]), fmaxf(redm[2], redm[3]));
        float e = __expf(lp - mx);
#pragma unroll
        for (int off = 1; off < 64; off <<= 1) e += __shfl_xor(e, off);
        if ((tid & 63) == 0) reds[wv] = e;
        __syncthreads();
        if (tid == 0)
            lik[bg + q] = mx + __logf(reds[0] + reds[1] + reds[2] + reds[3])
                        - 7.271269879190247f;  // -log(NMC) + LOG_VOL
        __syncthreads();
    }
}

// ---------------------------------------------------------------------------
// K5: gs MFMA -> xhat (768 blocks)
// ---------------------------------------------------------------------------
__global__ __launch_bounds__(256, 4) void k_gs(
    const float* __restrict__ yhat1,
    const float* __restrict__ w0, const float* __restrict__ b0,
    const float* __restrict__ w1bf,
    const float* __restrict__ b1, const float* __restrict__ w2,
    const float* __restrict__ b2, float* __restrict__ xhat)
{
    gs_mfma_body(blockIdx.x, yhat1, w0, b0, w1bf, b1, w2, b2, xhat);
}

// ---------------------------------------------------------------------------
// Fallback MC (ws too small for the table)
// ---------------------------------------------------------------------------
__global__ __launch_bounds__(256) void k_mc_direct(
    const float* __restrict__ yhat, const float* __restrict__ u2t,
    const float* __restrict__ eb, float* __restrict__ lik)
{
    __shared__ alignas(16) float sU[24 * 256];
    __shared__ float redm[4], reds[4];
    int tid = threadIdx.x;
    int wv = tid >> 6;
    int b = blockIdx.x;
    for (int i = tid; i < 1536; i += 256)
        ((float4*)sU)[i] = ((const float4*)u2t)[i];
    __syncthreads();

    float lp = 0.f;
    for (int c = 0; c < 24; ++c)
        lp += logpdf_ch(eb + c * 58, yhat[b * 24 + c] + sU[c * 256 + tid]);

    float m = lp;
#pragma unroll
    for (int off = 1; off < 64; off <<= 1) m = fmaxf(m, __shfl_xor(m, off));
    if ((tid & 63) == 0) redm[wv] = m;
    __syncthreads();
    float mx = fmaxf(fmaxf(redm[0], redm[1]), fmaxf(redm[2], redm[3]));
    float e = __expf(lp - mx);
#pragma unroll
    for (int off = 1; off < 64; off <<= 1) e += __shfl_xor(e, off);
    if ((tid & 63) == 0) reds[wv] = e;
    __syncthreads();
    if (tid == 0)
        lik[b] = mx + __logf(reds[0] + reds[1] + reds[2] + reds[3])
               - 7.271269879190247f;
}

// ---------------------------------------------------------------------------
extern "C" void kernel_launch(void* const* d_in, const int* in_sizes, int n_in,
                              void* d_out, int out_size, void* d_ws, size_t ws_size,
                              hipStream_t stream)
{
    (void)in_sizes; (void)n_in; (void)out_size;
    const float* x      = (const float*)d_in[0];
    const float* y_mean = (const float*)d_in[1];
    const float* u      = (const float*)d_in[2];
    const float* ga_w0  = (const float*)d_in[3];
    const float* ga_b0  = (const float*)d_in[4];
    const float* ga_w1  = (const float*)d_in[5];
    const float* ga_b1  = (const float*)d_in[6];
    const float* ga_w2  = (const float*)d_in[7];
    const float* ga_b2  = (const float*)d_in[8];
    const float* gs_w0  = (const float*)d_in[9];
    const float* gs_b0  = (const float*)d_in[10];
    const float* gs_w1  = (const float*)d_in[11];
    const float* gs_b1  = (const float*)d_in[12];
    const float* gs_w2  = (const float*)d_in[13];
    const float* gs_b2  = (const float*)d_in[14];
    const float* gac_w0 = (const float*)d_in[15];
    const float* gac_w1 = (const float*)d_in[16];
    const float* gac_w2 = (const float*)d_in[17];
    const float* gsc_w0 = (const float*)d_in[18];
    const float* gsc_w1 = (const float*)d_in[19];
    const float* gsc_w2 = (const float*)d_in[20];
    const float* eb_H0  = (const float*)d_in[21];
    const float* eb_H1  = (const float*)d_in[22];
    const float* eb_H2  = (const float*)d_in[23];
    const float* eb_H3  = (const float*)d_in[24];
    const float* eb_H4  = (const float*)d_in[25];
    const float* eb_b0  = (const float*)d_in[26];
    const float* eb_b1  = (const float*)d_in[27];
    const float* eb_b2  = (const float*)d_in[28];
    const float* eb_b3  = (const float*)d_in[29];
    const float* eb_b4  = (const float*)d_in[30];
    const float* eb_a0  = (const float*)d_in[31];
    const float* eb_a1  = (const float*)d_in[32];
    const float* eb_a2  = (const float*)d_in[33];
    const float* eb_a3  = (const float*)d_in[34];

    float* ws    = (float*)d_ws;
    float* y1    = ws + WS_Y1;
    float* yhat  = ws + WS_YHAT;
    float* yhat1 = ws + WS_YHAT1;
    float* ym    = ws + WS_YM;
    float* u2t   = ws + WS_U2T;
    float* eb    = ws + WS_EB;
    float* part  = ws + WS_PART;
    float* w1t   = ws + WS_W1T;
    float* w1bfGS  = ws + WS_W1BFGS;
    float* w1bfGSC = ws + WS_W1BFGSC;
    float* w2bfGSC = ws + WS_W2BFGSC;
    float* tbl   = ws + WS_TBL;
    float* xhat  = (float*)d_out;
    float* lik   = (float*)d_out + 98304;

    float* w1tGA  = w1t;
    float* w1tGAC = w1t + 12800;

    bool use_tbl = ws_size >= WS_END * sizeof(float);

    k_prep<<<237, 256, 0, stream>>>(eb_H0, eb_H1, eb_H2, eb_H3, eb_H4,
                                    eb_b0, eb_b1, eb_b2, eb_b3, eb_b4,
                                    eb_a0, eb_a1, eb_a2, eb_a3, u,
                                    ga_w1, gac_w1, gs_w1, gsc_w1, gsc_w2,
                                    eb, u2t, w1t, w1bfGS, w1bfGSC, w2bfGSC);
    if (use_tbl)
        k_ga_table<<<GA_BLOCKS + 24 * TBL_CAP / 4, 256, 0, stream>>>(
            x, ga_w0, ga_b0, w1tGA, ga_b1, ga_w2, ga_b2, y1, part,
            eb, u2t, tbl);
    else
        k_ga_table<<<GA_BLOCKS, 256, 0, stream>>>(
            x, ga_w0, ga_b0, w1tGA, ga_b1, ga_w2, ga_b2, y1, part,
            eb, u2t, tbl);
    k_mean_final<<<1, 256, 0, stream>>>(part, y_mean, ym);
    k_gac<<<NB / 8, 256, 0, stream>>>(y1, gac_w0, w1tGAC, gac_w2, ym, yhat);
    if (use_tbl) {
        k_gsc_mc<<<GSC_BLOCKS + NB / 4, 256, 0, stream>>>(
            yhat, gsc_w0, w1bfGSC, w2bfGSC, ym, yhat1,
            u2t, eb, tbl, lik);
    } else {
        k_gsc_mc<<<GSC_BLOCKS, 256, 0, stream>>>(
            yhat, gsc_w0, w1bfGSC, w2bfGSC, ym, yhat1,
            u2t, eb, tbl, lik);
        k_mc_direct<<<NB, 256, 0, stream>>>(yhat, u2t, eb, lik);
    }
    k_gs<<<GS_BLOCKS, 256, 0, stream>>>(yhat1, gs_w0, gs_b0, w1bfGS,
                                        gs_b1, gs_w2, gs_b2, xhat);
}

// Round 16
// 146.084 us; speedup vs baseline: 1.1440x; 1.1440x over previous
//
#include <hip/hip_runtime.h>
#include <hip/hip_bf16.h>
#include <math.h>
#include <limits.h>

// Problem dims
constexpr int NB    = 4096;   // batch
constexpr int ROWS2 = NB * 12;            // 49152 rows for the 2->100->100->2 MLPs
constexpr int GA_BLOCKS = ROWS2 / 128;    // 384 (128 rows/block, vector path)
constexpr int GS_BLOCKS = ROWS2 / 64;     // 768 (64 rows/block, MFMA path)
constexpr int GSC_BLOCKS = NB / 64;       // 64 (64 rows/block, MFMA path)
constexpr int TBL_CAP = 64;               // lattice slots per channel (fixed range)
constexpr int KBASE   = -32;              // fixed kmin for all channels

// workspace layout (float offsets)
constexpr size_t WS_Y1    = 0;              // NB*24
constexpr size_t WS_YHAT  = 98304;          // NB*24
constexpr size_t WS_YHAT1 = 196608;         // NB*24
constexpr size_t WS_YM    = 294912;         // 24
constexpr size_t WS_U2T   = 294936;         // 24*256 (transposed: [c][m])
constexpr size_t WS_EB    = 301080;         // 24*58 precomputed prior params
constexpr size_t WS_PART  = 302472;         // per-block mean partials
constexpr size_t WS_W1T   = 320904;         // 2 x [100][128] transposed w1 (ga,gac)
constexpr size_t WS_W1BFGS  = 346504;       // gs  w1 bf16 [112][128] (3584 f)
constexpr size_t WS_W1BFGSC = 350088;       // gsc w1 bf16 [128][128] (8192 f)
constexpr size_t WS_W2BFGSC = 358280;       // gsc w2 bf16 [32][128]  (2048 f)
constexpr size_t WS_TBL   = 360328;         // 24*64*256 table of log(pdf+1e-9)
constexpr size_t WS_END   = WS_TBL + 24 * TBL_CAP * 256;   // 753544 floats (~3.0 MB)

constexpr float STEP_ODD = 0.8660254037844386f;   // sqrt(3)/2
constexpr float INV_ODD  = 1.1547005383792517f;   // 2/sqrt(3)

typedef __attribute__((ext_vector_type(8))) short bf16x8;
typedef __attribute__((ext_vector_type(4))) float f32x4;

__device__ __forceinline__ float lrelu(float x) { return x >= 0.f ? x : 0.01f * x; }
__device__ __forceinline__ float rcp_fast(float x) { return __builtin_amdgcn_rcpf(x); }

__device__ __forceinline__ unsigned short f2bf(float f) {   // RNE f32 -> bf16
    unsigned b = __float_as_uint(f);
    b += 0x7FFFu + ((b >> 16) & 1u);
    return (unsigned short)(b >> 16);
}

__device__ __forceinline__ float tanh_fast(float x) {
    float xx = fminf(fmaxf(x, -15.f), 15.f);
    float e = __expf(xx + xx);
    return fmaf(-2.f, rcp_fast(e + 1.f), 1.f);
}
__device__ __forceinline__ float splus(float x) {
    return fmaxf(x, 0.f) + __logf(1.f + __expf(-fabsf(x)));
}
__device__ __forceinline__ float splus_precise(float x) {
    return fmaxf(x, 0.f) + log1pf(expf(-fabsf(x)));
}

__device__ __forceinline__ void fma4(float4& a, float h, const float4& w) {
    a.x = fmaf(h, w.x, a.x); a.y = fmaf(h, w.y, a.y);
    a.z = fmaf(h, w.z, a.z); a.w = fmaf(h, w.w, a.w);
}

// exact A2 hex lattice nearest-point quantizer; matches jnp.round (rint = RNE)
__device__ __forceinline__ void hexq(float p0, float p1, float& q0, float& q1) {
    const float S3 = 1.7320508075688772f;
    const float H3 = 0.8660254037844386f;
    float c00 = rintf(p0);
    float c01 = rintf(p1 / S3) * S3;
    float c10 = rintf(p0 - 0.5f) + 0.5f;
    float c11 = rintf((p1 - H3) / S3) * S3 + H3;
    float d0 = (p0 - c00) * (p0 - c00) + (p1 - c01) * (p1 - c01);
    float d1 = (p0 - c10) * (p0 - c10) + (p1 - c11) * (p1 - c11);
    bool take0 = d0 <= d1;
    q0 = take0 ? c00 : c10;
    q1 = take0 ? c01 : c11;
}

// per-channel prior chain: log(pdf + 1e-9) at point p, params P (58 floats)
__device__ __forceinline__ float logpdf_ch(const float* __restrict__ P, float p) {
    float w00 = P[0], w01 = P[1], w02 = P[2];
    float z0 = fmaf(w00, p, P[3]);
    float z1 = fmaf(w01, p, P[4]);
    float z2 = fmaf(w02, p, P[5]);
    float a0 = P[6], a1 = P[7], a2 = P[8];
    float e0 = tanh_fast(z0), e1 = tanh_fast(z1), e2 = tanh_fast(z2);
    float h0 = fmaf(a0, e0, z0), h1 = fmaf(a1, e1, z1), h2 = fmaf(a2, e2, z2);
    float t0 = w00 * fmaf(a0, fmaf(-e0, e0, 1.f), 1.f);
    float t1 = w01 * fmaf(a1, fmaf(-e1, e1, 1.f), 1.f);
    float t2 = w02 * fmaf(a2, fmaf(-e2, e2, 1.f), 1.f);

#define EB_LAYER(O)                                                            \
    {                                                                          \
        float z0n = fmaf(P[O+0], h0, fmaf(P[O+1], h1, fmaf(P[O+2], h2, P[O+9])));  \
        float z1n = fmaf(P[O+3], h0, fmaf(P[O+4], h1, fmaf(P[O+5], h2, P[O+10]))); \
        float z2n = fmaf(P[O+6], h0, fmaf(P[O+7], h1, fmaf(P[O+8], h2, P[O+11]))); \
        float s0 = fmaf(P[O+0], t0, fmaf(P[O+1], t1, P[O+2] * t2));            \
        float s1 = fmaf(P[O+3], t0, fmaf(P[O+4], t1, P[O+5] * t2));            \
        float s2 = fmaf(P[O+6], t0, fmaf(P[O+7], t1, P[O+8] * t2));            \
        float g0 = P[O+12], g1 = P[O+13], g2 = P[O+14];                        \
        float q0 = tanh_fast(z0n), q1 = tanh_fast(z1n), q2 = tanh_fast(z2n);   \
        h0 = fmaf(g0, q0, z0n); h1 = fmaf(g1, q1, z1n); h2 = fmaf(g2, q2, z2n); \
        t0 = s0 * fmaf(g0, fmaf(-q0, q0, 1.f), 1.f);                           \
        t1 = s1 * fmaf(g1, fmaf(-q1, q1, 1.f), 1.f);                           \
        t2 = s2 * fmaf(g2, fmaf(-q2, q2, 1.f), 1.f);                           \
    }
    EB_LAYER(9)
    EB_LAYER(24)
    EB_LAYER(39)
#undef EB_LAYER

    float L = fmaf(P[54], h0, fmaf(P[55], h1, fmaf(P[56], h2, P[57])));
    float T = fmaf(P[54], t0, fmaf(P[55], t1, P[56] * t2));
    float Lc = fminf(fmaxf(L, -30.f), 30.f);
    float sg = rcp_fast(1.f + __expf(-Lc));
    float pdf = sg * (1.f - sg) * T;
    return __logf(pdf + 1e-9f);
}

// ---------------------------------------------------------------------------
// K0: block 0: prior params + u2^T.
//     blocks 1..100:   transpose ga/gac w1 into [100][128] zero-padded f32.
//     blocks 101..156: gs  w1 -> bf16 [112][128] zero-padded.
//     blocks 157..220: gsc w1 -> bf16 [128][128] zero-padded.
//     blocks 221..236: gsc w2 -> bf16 [32][128]  zero-padded.
// ---------------------------------------------------------------------------
__global__ __launch_bounds__(256) void k_prep(
    const float* __restrict__ H0p, const float* __restrict__ H1p,
    const float* __restrict__ H2p, const float* __restrict__ H3p,
    const float* __restrict__ H4p,
    const float* __restrict__ b0p, const float* __restrict__ b1p,
    const float* __restrict__ b2p, const float* __restrict__ b3p,
    const float* __restrict__ b4p,
    const float* __restrict__ a0p, const float* __restrict__ a1p,
    const float* __restrict__ a2p, const float* __restrict__ a3p,
    const float* __restrict__ u,
    const float* __restrict__ w1ga, const float* __restrict__ w1gac,
    const float* __restrict__ w1gs, const float* __restrict__ w1gsc,
    const float* __restrict__ w2gsc,
    float* __restrict__ eb, float* __restrict__ u2t,
    float* __restrict__ w1t, float* __restrict__ w1bfGS,
    float* __restrict__ w1bfGSC, float* __restrict__ w2bfGSC)
{
    int tid = threadIdx.x;
    if (blockIdx.x > 0) {
        int t = blockIdx.x - 1;
        if (t < 100) {
            int m = t / 50;
            int o = (t % 50) * 256 + tid;       // 0..12799
            int k = o >> 7, i = o & 127;
            const float* src = (m == 0) ? w1ga : w1gac;
            w1t[m * 12800 + o] = (i < 100) ? src[i * 100 + k] : 0.f;
        } else if (t < 156) {
            int o = (t - 100) * 256 + tid;      // 0..14335
            int i = o >> 7, k = o & 127;
            float v = (i < 100 && k < 100) ? w1gs[i * 100 + k] : 0.f;
            ((unsigned short*)w1bfGS)[o] = f2bf(v);
        } else if (t < 220) {
            int o = (t - 156) * 256 + tid;      // 0..16383
            int i = o >> 7, k = o & 127;
            float v = (i < 100 && k < 100) ? w1gsc[i * 100 + k] : 0.f;
            ((unsigned short*)w1bfGSC)[o] = f2bf(v);
        } else {
            int o = (t - 220) * 256 + tid;      // 0..4095
            int c = o >> 7, k = o & 127;
            float v = (c < 24 && k < 100) ? w2gsc[c * 100 + k] : 0.f;
            ((unsigned short*)w2bfGSC)[o] = f2bf(v);
        }
        return;
    }
    if (tid < 24) {
        int c = tid;
        float* P = eb + c * 58;
        for (int j = 0; j < 3; ++j) P[j]      = splus_precise(H0p[c*3+j]);
        for (int j = 0; j < 3; ++j) P[3+j]    = b0p[c*3+j];
        for (int j = 0; j < 3; ++j) P[6+j]    = tanhf(a0p[c*3+j]);
        for (int j = 0; j < 9; ++j) P[9+j]    = splus_precise(H1p[c*9+j]);
        for (int j = 0; j < 3; ++j) P[18+j]   = b1p[c*3+j];
        for (int j = 0; j < 3; ++j) P[21+j]   = tanhf(a1p[c*3+j]);
        for (int j = 0; j < 9; ++j) P[24+j]   = splus_precise(H2p[c*9+j]);
        for (int j = 0; j < 3; ++j) P[33+j]   = b2p[c*3+j];
        for (int j = 0; j < 3; ++j) P[36+j]   = tanhf(a2p[c*3+j]);
        for (int j = 0; j < 9; ++j) P[39+j]   = splus_precise(H3p[c*9+j]);
        for (int j = 0; j < 3; ++j) P[48+j]   = b3p[c*3+j];
        for (int j = 0; j < 3; ++j) P[51+j]   = tanhf(a3p[c*3+j]);
        for (int j = 0; j < 3; ++j) P[54+j]   = splus_precise(H4p[c*3+j]);
        P[57] = b4p[c];
    }
    int m = tid;
    if (m < 256) {
        for (int j = 0; j < 12; ++j) {
            float a  = u[m*24 + 2*j];
            float bb = u[m*24 + 2*j + 1];
            float p0 = fmaf(0.5f, bb, a);
            float p1 = 0.8660254037844386f * bb;
            float q0, q1; hexq(p0, p1, q0, q1);
            u2t[(2*j)   * 256 + m] = p0 - q0;
            u2t[(2*j+1) * 256 + m] = p1 - q1;
        }
    }
}

// ---------------------------------------------------------------------------
// gemm2 body v2 (vector f32, ga path which feeds hexq): 128 rows/block.
// ---------------------------------------------------------------------------
template <int MEAN>
__device__ __forceinline__ void gemm2_body(
    int bid,
    const float* __restrict__ in,
    const float* __restrict__ w0, const float* __restrict__ b0,
    const float* __restrict__ w1t,
    const float* __restrict__ b1, const float* __restrict__ w2,
    const float* __restrict__ b2,
    float* __restrict__ out, float* __restrict__ partial)
{
    __shared__ alignas(16) float shT[100 * 128];  // h0T [k][row]; reused as red
    __shared__ float S[128][2];

    int tid = threadIdx.x;
    int row0 = bid * 128;

    for (int e = tid; e < 12800; e += 256) {
        int j = e >> 7, row = e & 127;
        float2 xv = ((const float2*)in)[row0 + row];
        shT[j * 128 + row] =
            lrelu(fmaf(w0[2*j], xv.x, fmaf(w0[2*j+1], xv.y, b0[j])));
    }

    int rg = tid >> 4;        // rows 8rg..8rg+7
    int cg = tid & 15;        // cols 8cg..8cg+7 (of 128)
    __syncthreads();

    float4 acc0[8], acc1[8];
    float4 zero4 = make_float4(0.f, 0.f, 0.f, 0.f);
#pragma unroll
    for (int r = 0; r < 8; ++r) { acc0[r] = zero4; acc1[r] = zero4; }

    const float4* wg = (const float4*)w1t + cg * 2;
    const float4* hp = (const float4*)shT + rg * 2;
    float4 wa0 = wg[0],  wa1 = wg[1];
    float4 wb0 = wg[32], wb1 = wg[33];
#pragma unroll 2
    for (int k = 0; k < 100; ++k) {
        float4 wn0 = wg[(k + 2) * 32];
        float4 wn1 = wg[(k + 2) * 32 + 1];
        float4 ha = hp[k * 32];
        float4 hb = hp[k * 32 + 1];
        fma4(acc0[0], ha.x, wa0); fma4(acc1[0], ha.x, wa1);
        fma4(acc0[1], ha.y, wa0); fma4(acc1[1], ha.y, wa1);
        fma4(acc0[2], ha.z, wa0); fma4(acc1[2], ha.z, wa1);
        fma4(acc0[3], ha.w, wa0); fma4(acc1[3], ha.w, wa1);
        fma4(acc0[4], hb.x, wa0); fma4(acc1[4], hb.x, wa1);
        fma4(acc0[5], hb.y, wa0); fma4(acc1[5], hb.y, wa1);
        fma4(acc0[6], hb.z, wa0); fma4(acc1[6], hb.z, wa1);
        fma4(acc0[7], hb.w, wa0); fma4(acc1[7], hb.w, wa1);
        wa0 = wb0; wa1 = wb1; wb0 = wn0; wb1 = wn1;
    }
    __syncthreads();

    float b1v[8], w20v[8], w21v[8];
    int c0 = cg * 8;
#pragma unroll
    for (int e = 0; e < 8; ++e) {
        int c = c0 + e;
        bool v = (c < 100);
        b1v[e]  = v ? b1[c] : 0.f;
        w20v[e] = v ? w2[c] : 0.f;
        w21v[e] = v ? w2[100 + c] : 0.f;
    }
    float* red = shT;         // [128][2][16]
#pragma unroll
    for (int r = 0; r < 8; ++r) {
        float a0 = lrelu(acc0[r].x + b1v[0]);
        float a1 = lrelu(acc0[r].y + b1v[1]);
        float a2 = lrelu(acc0[r].z + b1v[2]);
        float a3 = lrelu(acc0[r].w + b1v[3]);
        float a4 = lrelu(acc1[r].x + b1v[4]);
        float a5 = lrelu(acc1[r].y + b1v[5]);
        float a6 = lrelu(acc1[r].z + b1v[6]);
        float a7 = lrelu(acc1[r].w + b1v[7]);
        float y0 = a0*w20v[0] + a1*w20v[1] + a2*w20v[2] + a3*w20v[3]
                 + a4*w20v[4] + a5*w20v[5] + a6*w20v[6] + a7*w20v[7];
        float y1 = a0*w21v[0] + a1*w21v[1] + a2*w21v[2] + a3*w21v[3]
                 + a4*w21v[4] + a5*w21v[5] + a6*w21v[6] + a7*w21v[7];
        int row = rg * 8 + r;
        red[(row * 2) * 16 + cg]     = y0;
        red[(row * 2 + 1) * 16 + cg] = y1;
    }
    __syncthreads();
    {
        int row = tid >> 1, p = tid & 1;
        const float4* rp = (const float4*)&red[(row * 2 + p) * 16];
        float4 v0 = rp[0], v1 = rp[1], v2 = rp[2], v3 = rp[3];
        float s = ((v0.x + v0.y) + (v0.z + v0.w))
                + ((v1.x + v1.y) + (v1.z + v1.w))
                + ((v2.x + v2.y) + (v2.z + v2.w))
                + ((v3.x + v3.y) + (v3.z + v3.w));
        float y = s + b2[p];
        out[(row0 + row) * 2 + p] = y;
        if (MEAN) S[row][p] = y;
    }
    if (MEAN) {
        __syncthreads();
        if (tid < 24) {
            int j = tid >> 1, par = tid & 1;
            int base = row0 % 12;
            int k0 = (j - base + 144) % 12;
            float s = 0.f;
            for (int k = k0; k < 128; k += 12) s += S[k][par];
            partial[bid * 24 + tid] = s;
        }
    }
}

// ---------------------------------------------------------------------------
// gs MFMA body (validated in R14): 64 rows/block, 4 waves x 16-row M-tiles.
// ---------------------------------------------------------------------------
__device__ __forceinline__ void gs_mfma_body(
    int bid,
    const float* __restrict__ in,
    const float* __restrict__ w0, const float* __restrict__ b0,
    const float* __restrict__ w1bf,
    const float* __restrict__ b1, const float* __restrict__ w2,
    const float* __restrict__ b2,
    float* __restrict__ out)
{
    int tid = threadIdx.x;
    int lane = tid & 63, wv = tid >> 6;
    int rsel = lane & 15;
    int kgrp = lane >> 4;
    int row0w = bid * 64 + wv * 16;

    float2 xv = ((const float2*)in)[row0w + rsel];

    bf16x8 afr[4];
#pragma unroll
    for (int kb = 0; kb < 4; ++kb) {
#pragma unroll
        for (int j8 = 0; j8 < 8; ++j8) {
            int j = kb * 32 + kgrp * 8 + j8;
            float h = 0.f;
            if (j < 100)
                h = lrelu(fmaf(w0[2*j], xv.x, fmaf(w0[2*j+1], xv.y, b0[j])));
            afr[kb][j8] = (short)f2bf(h);
        }
    }

    const unsigned short* w1u = (const unsigned short*)w1bf;
    f32x4 acc[7];
#pragma unroll
    for (int n = 0; n < 7; ++n) acc[n] = (f32x4){0.f, 0.f, 0.f, 0.f};
#pragma unroll
    for (int kb = 0; kb < 4; ++kb) {
#pragma unroll
        for (int n = 0; n < 7; ++n) {
            bf16x8 bfr = *(const bf16x8*)(w1u + (n * 16 + rsel) * 128
                                              + kb * 32 + kgrp * 8);
            acc[n] = __builtin_amdgcn_mfma_f32_16x16x32_bf16(afr[kb], bfr,
                                                             acc[n], 0, 0, 0);
        }
    }

    float py0[4] = {0.f, 0.f, 0.f, 0.f}, py1[4] = {0.f, 0.f, 0.f, 0.f};
#pragma unroll
    for (int n = 0; n < 7; ++n) {
        int i = n * 16 + rsel;
        bool v = (i < 100);
        float b1v = v ? b1[i] : 0.f;
        float w20 = v ? w2[i] : 0.f;
        float w21 = v ? w2[100 + i] : 0.f;
#pragma unroll
        for (int r = 0; r < 4; ++r) {
            float a = lrelu(acc[n][r] + b1v);
            py0[r] = fmaf(a, w20, py0[r]);
            py1[r] = fmaf(a, w21, py1[r]);
        }
    }
#pragma unroll
    for (int r = 0; r < 4; ++r) {
#pragma unroll
        for (int off = 1; off < 16; off <<= 1) {
            py0[r] += __shfl_xor(py0[r], off);
            py1[r] += __shfl_xor(py1[r], off);
        }
    }
    if (rsel == 0) {
#pragma unroll
        for (int r = 0; r < 4; ++r) {
            int row = row0w + kgrp * 4 + r;
            out[row * 2]     = py0[r] + b2[0];
            out[row * 2 + 1] = py1[r] + b2[1];
        }
    }
}

// ---------------------------------------------------------------------------
// K1: merged dispatch: blocks [0,384) = ga GEMM (y1 + mean partials),
// blocks [384, 384+384) = prior table build (4 v-slots per block).
// ---------------------------------------------------------------------------
__global__ __launch_bounds__(256, 2) void k_ga_table(
    const float* __restrict__ in,
    const float* __restrict__ w0, const float* __restrict__ b0,
    const float* __restrict__ w1t,
    const float* __restrict__ b1, const float* __restrict__ w2,
    const float* __restrict__ b2,
    float* __restrict__ out, float* __restrict__ partial,
    const float* __restrict__ eb, const float* __restrict__ u2t,
    float* __restrict__ tbl)
{
    if (blockIdx.x < (unsigned)GA_BLOCKS) {
        gemm2_body<1>(blockIdx.x, in, w0, b0, w1t, b1, w2, b2, out, partial);
    } else {
        int cv4 = blockIdx.x - GA_BLOCKS;      // 0..383
        int c = cv4 >> 4, vg = (cv4 & 15) * 4;
        int m = threadIdx.x;
        float step = (c & 1) ? STEP_ODD : 0.5f;
        float uv = u2t[c * 256 + m];
        const float* P = eb + c * 58;
#pragma unroll
        for (int dv = 0; dv < 4; ++dv) {
            int v = vg + dv;
            float val = (float)(KBASE + v) * step;
            tbl[(c * TBL_CAP + v) * 256 + m] = logpdf_ch(P, val + uv);
        }
    }
}

// ---------------------------------------------------------------------------
// K2: finish the EMA mean from 384 per-block partials (1 block, sub-us)
// ---------------------------------------------------------------------------
__global__ __launch_bounds__(256) void k_mean_final(
    const float* __restrict__ partial, const float* __restrict__ y_mean,
    float* __restrict__ ym)
{
    int tid = threadIdx.x;
    int c = tid >> 3, s = tid & 7;
    float v = 0.f;
    if (c < 24)
        for (int g = s; g < GA_BLOCKS; g += 8) v += partial[g * 24 + c];
    v += __shfl_xor(v, 1); v += __shfl_xor(v, 2); v += __shfl_xor(v, 4);
    if (c < 24 && s == 0)
        ym[c] = fmaf(0.05f, y_mean[c], 0.95f * (v * (1.0f / NB)));
}

// ---------------------------------------------------------------------------
// K3: gac only (f32, feeds hexq). 8 rows/block, 512 blocks.
// yhat = hexq(gac(y1 - ym)).
// ---------------------------------------------------------------------------
__global__ __launch_bounds__(256, 4) void k_gac(
    const float* __restrict__ y1,
    const float* __restrict__ w0A, const float* __restrict__ w1tA,
    const float* __restrict__ w2A,
    const float* __restrict__ ymg,
    float* __restrict__ yhat)
{
    __shared__ float sw0[2400];
    __shared__ float sw2[2400];
    __shared__ float sX[8 * 25];
    __shared__ float sO[8 * 25];
    __shared__ alignas(16) float h0[100 * 8];   // [j][r]
    __shared__ float h1[100 * 8];               // [i][r]
    __shared__ float symL[24];

    int tid = threadIdx.x;
    int row0 = blockIdx.x * 8;

    if (tid < 24) symL[tid] = ymg[tid];
    for (int t = tid; t < 2400; t += 256) {
        sw0[t] = w0A[t];
        sw2[t] = w2A[t];
    }
    __syncthreads();
    for (int e = tid; e < 192; e += 256) {
        int r = e / 24, c = e - r * 24;
        sX[r * 25 + c] = y1[row0 * 24 + e] - symL[c];
    }
    __syncthreads();

    int ii = tid & 127, rg = tid >> 7;

    // layer 0
    for (int e = tid; e < 800; e += 256) {
        int j = e >> 3, r = e & 7;
        const float* wr = sw0 + j * 24;
        const float* xr = sX + r * 25;
        float a = 0.f, b = 0.f;
#pragma unroll
        for (int k = 0; k < 24; k += 2) {
            a = fmaf(wr[k],     xr[k],     a);
            b = fmaf(wr[k + 1], xr[k + 1], b);
        }
        h0[j * 8 + r] = splus(a + b);
    }
    __syncthreads();

    // layer 1 (w1t column-coalesced from L2)
    {
        float4 a = make_float4(0.f, 0.f, 0.f, 0.f);
        const float* wc = w1tA + ii;
        const float4* h4 = (const float4*)h0 + rg;
#pragma unroll 4
        for (int j = 0; j < 100; ++j) {
            float w = wc[j * 128];
            float4 h = h4[j * 2];
            a.x = fmaf(w, h.x, a.x); a.y = fmaf(w, h.y, a.y);
            a.z = fmaf(w, h.z, a.z); a.w = fmaf(w, h.w, a.w);
        }
        if (ii < 100) {
            h1[ii * 8 + rg * 4]     = splus(a.x);
            h1[ii * 8 + rg * 4 + 1] = splus(a.y);
            h1[ii * 8 + rg * 4 + 2] = splus(a.z);
            h1[ii * 8 + rg * 4 + 3] = splus(a.w);
        }
    }
    __syncthreads();

    // layer 2
    if (tid < 192) {
        int c = tid >> 3, r = tid & 7;
        const float* w2r = sw2 + c * 100;
        float s = 0.f, s2 = 0.f;
#pragma unroll 4
        for (int i = 0; i < 100; i += 2) {
            s  = fmaf(w2r[i],     h1[i * 8 + r],       s);
            s2 = fmaf(w2r[i + 1], h1[(i + 1) * 8 + r], s2);
        }
        sO[r * 25 + c] = s + s2;
    }
    __syncthreads();
    if (tid < 96) {
        int pr = tid >> 3, r = tid & 7;
        float v0 = sO[r * 25 + 2*pr], v1 = sO[r * 25 + 2*pr + 1];
        float q0, q1; hexq(v0, v1, q0, q1);
        yhat[(row0 + r) * 24 + 2*pr]     = q0;
        yhat[(row0 + r) * 24 + 2*pr + 1] = q1;
    }
}

// ---------------------------------------------------------------------------
// K4: gsc MFMA (own kernel -> clean regalloc, no spill).
// yhat (4096x24) -> 100 (splus) -> 100 (splus) -> 24, +ym. bf16-safe
// (post-quantization). 64 rows/block, 4 waves x 16-row M-tiles.
// ---------------------------------------------------------------------------
__global__ __launch_bounds__(256, 2) void k_gsc(
    const float* __restrict__ yhat,
    const float* __restrict__ w0,
    const float* __restrict__ w1bfC, const float* __restrict__ w2bfC,
    const float* __restrict__ ymg, float* __restrict__ yhat1)
{
    __shared__ float h1L[4 * 128 * 16];       // 32 KB
    int tid = threadIdx.x;
    int lane = tid & 63, wv = tid >> 6;
    int rsel = lane & 15;
    int kgrp = lane >> 4;
    int row0w = blockIdx.x * 64 + wv * 16;

    float xr[24];
    const float4* xp = (const float4*)(yhat + (row0w + rsel) * 24);
#pragma unroll
    for (int k4 = 0; k4 < 6; ++k4) {
        float4 t = xp[k4];
        xr[4*k4] = t.x; xr[4*k4+1] = t.y; xr[4*k4+2] = t.z; xr[4*k4+3] = t.w;
    }

    // layer 0 (f32) -> A fragments
    bf16x8 afr[4];
#pragma unroll
    for (int kb = 0; kb < 4; ++kb) {
#pragma unroll
        for (int j8 = 0; j8 < 8; ++j8) {
            int j = kb * 32 + kgrp * 8 + j8;
            float h = 0.f;
            if (j < 100) {
                const float* wr = w0 + j * 24;
                float a = 0.f, b = 0.f;
#pragma unroll
                for (int k = 0; k < 24; k += 2) {
                    a = fmaf(wr[k],     xr[k],     a);
                    b = fmaf(wr[k + 1], xr[k + 1], b);
                }
                h = splus(a + b);
            }
            afr[kb][j8] = (short)f2bf(h);
        }
    }

    // layer 1: 8 N-tiles x 4 K-blocks
    const unsigned short* w1u = (const unsigned short*)w1bfC;
    f32x4 acc[8];
#pragma unroll
    for (int n = 0; n < 8; ++n) acc[n] = (f32x4){0.f, 0.f, 0.f, 0.f};
#pragma unroll
    for (int kb = 0; kb < 4; ++kb) {
#pragma unroll
        for (int n = 0; n < 8; ++n) {
            bf16x8 bfr = *(const bf16x8*)(w1u + (n * 16 + rsel) * 128
                                              + kb * 32 + kgrp * 8);
            acc[n] = __builtin_amdgcn_mfma_f32_16x16x32_bf16(afr[kb], bfr,
                                                             acc[n], 0, 0, 0);
        }
    }

    // splus -> LDS transpose (D: col=rsel -> i = n*16+rsel, row = kgrp*4+r)
    float* hl = h1L + wv * 128 * 16;
#pragma unroll
    for (int n = 0; n < 8; ++n) {
        int i = n * 16 + rsel;
        float v0 = (i < 100) ? splus(acc[n][0]) : 0.f;
        float v1 = (i < 100) ? splus(acc[n][1]) : 0.f;
        float v2 = (i < 100) ? splus(acc[n][2]) : 0.f;
        float v3 = (i < 100) ? splus(acc[n][3]) : 0.f;
        hl[i * 16 + kgrp * 4]     = v0;
        hl[i * 16 + kgrp * 4 + 1] = v1;
        hl[i * 16 + kgrp * 4 + 2] = v2;
        hl[i * 16 + kgrp * 4 + 3] = v3;
    }
    __syncthreads();

    // layer 2 A-frags from LDS (row = rsel, k = kb*32+kgrp*8+j8)
    bf16x8 afr2[4];
#pragma unroll
    for (int kb = 0; kb < 4; ++kb) {
#pragma unroll
        for (int j8 = 0; j8 < 8; ++j8) {
            int i = kb * 32 + kgrp * 8 + j8;
            afr2[kb][j8] = (short)f2bf(hl[i * 16 + rsel]);
        }
    }
    const unsigned short* w2u = (const unsigned short*)w2bfC;
    f32x4 acc2[2];
    acc2[0] = (f32x4){0.f, 0.f, 0.f, 0.f};
    acc2[1] = (f32x4){0.f, 0.f, 0.f, 0.f};
#pragma unroll
    for (int kb = 0; kb < 4; ++kb) {
#pragma unroll
        for (int n = 0; n < 2; ++n) {
            bf16x8 bfr = *(const bf16x8*)(w2u + (n * 16 + rsel) * 128
                                              + kb * 32 + kgrp * 8);
            acc2[n] = __builtin_amdgcn_mfma_f32_16x16x32_bf16(afr2[kb], bfr,
                                                              acc2[n], 0, 0, 0);
        }
    }

#pragma unroll
    for (int n = 0; n < 2; ++n) {
        int c = n * 16 + rsel;
        if (c < 24) {
            float ym = ymg[c];
#pragma unroll
            for (int r = 0; r < 4; ++r)
                yhat1[(row0w + kgrp * 4 + r) * 24 + c] = acc2[n][r] + ym;
        }
    }
}

// ---------------------------------------------------------------------------
// K5 (merged, R14-validated): blocks [0,768) = gs MFMA -> xhat;
// blocks [768,768+1024) = MC likelihood (4 rows/block, clamped gathers).
// ---------------------------------------------------------------------------
__global__ __launch_bounds__(256, 4) void k_gs_mc(
    const float* __restrict__ yhat1,
    const float* __restrict__ w0, const float* __restrict__ b0,
    const float* __restrict__ w1bf,
    const float* __restrict__ b1, const float* __restrict__ w2,
    const float* __restrict__ b2, float* __restrict__ xhat,
    const float* __restrict__ yhat, const float* __restrict__ u2t,
    const float* __restrict__ eb,
    const float* __restrict__ tbl, float* __restrict__ lik)
{
    if (blockIdx.x < (unsigned)GS_BLOCKS) {
        gs_mfma_body(blockIdx.x, yhat1, w0, b0, w1bf, b1, w2, b2, xhat);
        return;
    }
    __shared__ float sy[4 * 24];
    __shared__ float redm[4], reds[4];
    int tid = threadIdx.x;
    int wv = tid >> 6;
    int bg = (blockIdx.x - GS_BLOCKS) * 4;

    if (tid < 96) sy[tid] = yhat[bg * 24 + tid];
    __syncthreads();

    for (int q = 0; q < 4; ++q) {
        float lp = 0.f;
        unsigned miss = 0;
#pragma unroll
        for (int c = 0; c < 24; ++c) {
            float yv = sy[q * 24 + c];
            float inv = (c & 1) ? INV_ODD : 2.0f;
            int k = (int)rintf(yv * inv);
            int idx = k - KBASE;
            bool ok = (idx >= 0 && idx < TBL_CAP);
            int idq = min(max(idx, 0), TBL_CAP - 1);
            float tv = tbl[(c * TBL_CAP + idq) * 256 + tid];  // unconditional
            lp += ok ? tv : 0.f;
            if (!ok) miss |= (1u << c);
        }
        while (miss) {
            int c = __ffs(miss) - 1;
            miss &= miss - 1;
            lp += logpdf_ch(eb + c * 58, sy[q * 24 + c] + u2t[c * 256 + tid]);
        }

        float m = lp;
#pragma unroll
        for (int off = 1; off < 64; off <<= 1) m = fmaxf(m, __shfl_xor(m, off));
        if ((tid & 63) == 0) redm[wv] = m;
        __syncthreads();
        float mx = fmaxf(fmaxf(redm[0], redm[1]), fmaxf(redm[2], redm[3]));
        float e = __expf(lp - mx);
#pragma unroll
        for (int off = 1; off < 64; off <<= 1) e += __shfl_xor(e, off);
        if ((tid & 63) == 0) reds[wv] = e;
        __syncthreads();
        if (tid == 0)
            lik[bg + q] = mx + __logf(reds[0] + reds[1] + reds[2] + reds[3])
                        - 7.271269879190247f;  // -log(NMC) + LOG_VOL
        __syncthreads();
    }
}

// ---------------------------------------------------------------------------
// Fallback MC (ws too small for the table)
// ---------------------------------------------------------------------------
__global__ __launch_bounds__(256) void k_mc_direct(
    const float* __restrict__ yhat, const float* __restrict__ u2t,
    const float* __restrict__ eb, float* __restrict__ lik)
{
    __shared__ alignas(16) float sU[24 * 256];
    __shared__ float redm[4], reds[4];
    int tid = threadIdx.x;
    int wv = tid >> 6;
    int b = blockIdx.x;
    for (int i = tid; i < 1536; i += 256)
        ((float4*)sU)[i] = ((const float4*)u2t)[i];
    __syncthreads();

    float lp = 0.f;
    for (int c = 0; c < 24; ++c)
        lp += logpdf_ch(eb + c * 58, yhat[b * 24 + c] + sU[c * 256 + tid]);

    float m = lp;
#pragma unroll
    for (int off = 1; off < 64; off <<= 1) m = fmaxf(m, __shfl_xor(m, off));
    if ((tid & 63) == 0) redm[wv] = m;
    __syncthreads();
    float mx = fmaxf(fmaxf(redm[0], redm[1]), fmaxf(redm[2], redm[3]));
    float e = __expf(lp - mx);
#pragma unroll
    for (int off = 1; off < 64; off <<= 1) e += __shfl_xor(e, off);
    if ((tid & 63) == 0) reds[wv] = e;
    __syncthreads();
    if (tid == 0)
        lik[b] = mx + __logf(reds[0] + reds[1] + reds[2] + reds[3])
               - 7.271269879190247f;
}

__global__ __launch_bounds__(256, 4) void k_gs_only(
    const float* __restrict__ yhat1,
    const float* __restrict__ w0, const float* __restrict__ b0,
    const float* __restrict__ w1bf,
    const float* __restrict__ b1, const float* __restrict__ w2,
    const float* __restrict__ b2, float* __restrict__ xhat)
{
    gs_mfma_body(blockIdx.x, yhat1, w0, b0, w1bf, b1, w2, b2, xhat);
}

// ---------------------------------------------------------------------------
extern "C" void kernel_launch(void* const* d_in, const int* in_sizes, int n_in,
                              void* d_out, int out_size, void* d_ws, size_t ws_size,
                              hipStream_t stream)
{
    (void)in_sizes; (void)n_in; (void)out_size;
    const float* x      = (const float*)d_in[0];
    const float* y_mean = (const float*)d_in[1];
    const float* u      = (const float*)d_in[2];
    const float* ga_w0  = (const float*)d_in[3];
    const float* ga_b0  = (const float*)d_in[4];
    const float* ga_w1  = (const float*)d_in[5];
    const float* ga_b1  = (const float*)d_in[6];
    const float* ga_w2  = (const float*)d_in[7];
    const float* ga_b2  = (const float*)d_in[8];
    const float* gs_w0  = (const float*)d_in[9];
    const float* gs_b0  = (const float*)d_in[10];
    const float* gs_w1  = (const float*)d_in[11];
    const float* gs_b1  = (const float*)d_in[12];
    const float* gs_w2  = (const float*)d_in[13];
    const float* gs_b2  = (const float*)d_in[14];
    const float* gac_w0 = (const float*)d_in[15];
    const float* gac_w1 = (const float*)d_in[16];
    const float* gac_w2 = (const float*)d_in[17];
    const float* gsc_w0 = (const float*)d_in[18];
    const float* gsc_w1 = (const float*)d_in[19];
    const float* gsc_w2 = (const float*)d_in[20];
    const float* eb_H0  = (const float*)d_in[21];
    const float* eb_H1  = (const float*)d_in[22];
    const float* eb_H2  = (const float*)d_in[23];
    const float* eb_H3  = (const float*)d_in[24];
    const float* eb_H4  = (const float*)d_in[25];
    const float* eb_b0  = (const float*)d_in[26];
    const float* eb_b1  = (const float*)d_in[27];
    const float* eb_b2  = (const float*)d_in[28];
    const float* eb_b3  = (const float*)d_in[29];
    const float* eb_b4  = (const float*)d_in[30];
    const float* eb_a0  = (const float*)d_in[31];
    const float* eb_a1  = (const float*)d_in[32];
    const float* eb_a2  = (const float*)d_in[33];
    const float* eb_a3  = (const float*)d_in[34];

    float* ws    = (float*)d_ws;
    float* y1    = ws + WS_Y1;
    float* yhat  = ws + WS_YHAT;
    float* yhat1 = ws + WS_YHAT1;
    float* ym    = ws + WS_YM;
    float* u2t   = ws + WS_U2T;
    float* eb    = ws + WS_EB;
    float* part  = ws + WS_PART;
    float* w1t   = ws + WS_W1T;
    float* w1bfGS  = ws + WS_W1BFGS;
    float* w1bfGSC = ws + WS_W1BFGSC;
    float* w2bfGSC = ws + WS_W2BFGSC;
    float* tbl   = ws + WS_TBL;
    float* xhat  = (float*)d_out;
    float* lik   = (float*)d_out + 98304;

    float* w1tGA  = w1t;
    float* w1tGAC = w1t + 12800;

    bool use_tbl = ws_size >= WS_END * sizeof(float);

    k_prep<<<237, 256, 0, stream>>>(eb_H0, eb_H1, eb_H2, eb_H3, eb_H4,
                                    eb_b0, eb_b1, eb_b2, eb_b3, eb_b4,
                                    eb_a0, eb_a1, eb_a2, eb_a3, u,
                                    ga_w1, gac_w1, gs_w1, gsc_w1, gsc_w2,
                                    eb, u2t, w1t, w1bfGS, w1bfGSC, w2bfGSC);
    if (use_tbl)
        k_ga_table<<<GA_BLOCKS + 24 * TBL_CAP / 4, 256, 0, stream>>>(
            x, ga_w0, ga_b0, w1tGA, ga_b1, ga_w2, ga_b2, y1, part,
            eb, u2t, tbl);
    else
        k_ga_table<<<GA_BLOCKS, 256, 0, stream>>>(
            x, ga_w0, ga_b0, w1tGA, ga_b1, ga_w2, ga_b2, y1, part,
            eb, u2t, tbl);
    k_mean_final<<<1, 256, 0, stream>>>(part, y_mean, ym);
    k_gac<<<NB / 8, 256, 0, stream>>>(y1, gac_w0, w1tGAC, gac_w2, ym, yhat);
    k_gsc<<<GSC_BLOCKS, 256, 0, stream>>>(yhat, gsc_w0, w1bfGSC, w2bfGSC,
                                          ym, yhat1);
    if (use_tbl) {
        k_gs_mc<<<GS_BLOCKS + NB / 4, 256, 0, stream>>>(
            yhat1, gs_w0, gs_b0, w1bfGS, gs_b1, gs_w2, gs_b2, xhat,
            yhat, u2t, eb, tbl, lik);
    } else {
        k_gs_only<<<GS_BLOCKS, 256, 0, stream>>>(
            yhat1, gs_w0, gs_b0, w1bfGS, gs_b1, gs_w2, gs_b2, xhat);
        k_mc_direct<<<NB, 256, 0, stream>>>(yhat, u2t, eb, lik);
    }
}

// Round 17
// 142.248 us; speedup vs baseline: 1.1748x; 1.0270x over previous
//
#include <hip/hip_runtime.h>
#include <hip/hip_bf16.h>
#include <math.h>
#include <limits.h>

// Problem dims
constexpr int NB    = 4096;   // batch
constexpr int ROWS2 = NB * 12;            // 49152 rows for the 2->100->100->2 MLPs
constexpr int GA_BLOCKS = ROWS2 / 128;    // 384 (128 rows/block, vector path)
constexpr int GS_BLOCKS = ROWS2 / 64;     // 768 (64 rows/block, MFMA path)
constexpr int GSC_BLOCKS = NB / 64;       // 64 (64 rows/block, MFMA path)
constexpr int TBL_CAP = 64;               // lattice slots per channel (fixed range)
constexpr int KBASE   = -32;              // fixed kmin for all channels

// workspace layout (float offsets)
constexpr size_t WS_Y1    = 0;              // NB*24
constexpr size_t WS_YHAT  = 98304;          // NB*24
constexpr size_t WS_YHAT1 = 196608;         // NB*24
constexpr size_t WS_YM    = 294912;         // 24
constexpr size_t WS_U2T   = 294936;         // 24*256 (transposed: [c][m])
constexpr size_t WS_EB    = 301080;         // 24*58 precomputed prior params
constexpr size_t WS_PART  = 302472;         // per-block mean partials
constexpr size_t WS_W1T   = 320904;         // 2 x [100][128] transposed w1 (ga,gac)
constexpr size_t WS_W1BFGS  = 346504;       // gs  w1 bf16 [112][128] (3584 f)
constexpr size_t WS_W1BFGSC = 350088;       // gsc w1 bf16 [128][128] (8192 f)
constexpr size_t WS_W2BFGSC = 358280;       // gsc w2 bf16 [32][128]  (2048 f)
constexpr size_t WS_TBL   = 360328;         // 24*64*256 table of log(pdf+1e-9)
constexpr size_t WS_END   = WS_TBL + 24 * TBL_CAP * 256;   // 753544 floats (~3.0 MB)

constexpr float STEP_ODD = 0.8660254037844386f;   // sqrt(3)/2
constexpr float INV_ODD  = 1.1547005383792517f;   // 2/sqrt(3)

typedef __attribute__((ext_vector_type(8))) short bf16x8;
typedef __attribute__((ext_vector_type(4))) float f32x4;

__device__ __forceinline__ float lrelu(float x) { return x >= 0.f ? x : 0.01f * x; }
__device__ __forceinline__ float rcp_fast(float x) { return __builtin_amdgcn_rcpf(x); }

__device__ __forceinline__ unsigned short f2bf(float f) {   // RNE f32 -> bf16
    unsigned b = __float_as_uint(f);
    b += 0x7FFFu + ((b >> 16) & 1u);
    return (unsigned short)(b >> 16);
}

__device__ __forceinline__ float tanh_fast(float x) {
    float xx = fminf(fmaxf(x, -15.f), 15.f);
    float e = __expf(xx + xx);
    return fmaf(-2.f, rcp_fast(e + 1.f), 1.f);
}
__device__ __forceinline__ float splus(float x) {
    return fmaxf(x, 0.f) + __logf(1.f + __expf(-fabsf(x)));
}
__device__ __forceinline__ float splus_precise(float x) {
    return fmaxf(x, 0.f) + log1pf(expf(-fabsf(x)));
}

__device__ __forceinline__ void fma4(float4& a, float h, const float4& w) {
    a.x = fmaf(h, w.x, a.x); a.y = fmaf(h, w.y, a.y);
    a.z = fmaf(h, w.z, a.z); a.w = fmaf(h, w.w, a.w);
}

// exact A2 hex lattice nearest-point quantizer; matches jnp.round (rint = RNE)
__device__ __forceinline__ void hexq(float p0, float p1, float& q0, float& q1) {
    const float S3 = 1.7320508075688772f;
    const float H3 = 0.8660254037844386f;
    float c00 = rintf(p0);
    float c01 = rintf(p1 / S3) * S3;
    float c10 = rintf(p0 - 0.5f) + 0.5f;
    float c11 = rintf((p1 - H3) / S3) * S3 + H3;
    float d0 = (p0 - c00) * (p0 - c00) + (p1 - c01) * (p1 - c01);
    float d1 = (p0 - c10) * (p0 - c10) + (p1 - c11) * (p1 - c11);
    bool take0 = d0 <= d1;
    q0 = take0 ? c00 : c10;
    q1 = take0 ? c01 : c11;
}

// per-channel prior chain: log(pdf + 1e-9) at point p, params P (58 floats)
__device__ __forceinline__ float logpdf_ch(const float* __restrict__ P, float p) {
    float w00 = P[0], w01 = P[1], w02 = P[2];
    float z0 = fmaf(w00, p, P[3]);
    float z1 = fmaf(w01, p, P[4]);
    float z2 = fmaf(w02, p, P[5]);
    float a0 = P[6], a1 = P[7], a2 = P[8];
    float e0 = tanh_fast(z0), e1 = tanh_fast(z1), e2 = tanh_fast(z2);
    float h0 = fmaf(a0, e0, z0), h1 = fmaf(a1, e1, z1), h2 = fmaf(a2, e2, z2);
    float t0 = w00 * fmaf(a0, fmaf(-e0, e0, 1.f), 1.f);
    float t1 = w01 * fmaf(a1, fmaf(-e1, e1, 1.f), 1.f);
    float t2 = w02 * fmaf(a2, fmaf(-e2, e2, 1.f), 1.f);

#define EB_LAYER(O)                                                            \
    {                                                                          \
        float z0n = fmaf(P[O+0], h0, fmaf(P[O+1], h1, fmaf(P[O+2], h2, P[O+9])));  \
        float z1n = fmaf(P[O+3], h0, fmaf(P[O+4], h1, fmaf(P[O+5], h2, P[O+10]))); \
        float z2n = fmaf(P[O+6], h0, fmaf(P[O+7], h1, fmaf(P[O+8], h2, P[O+11]))); \
        float s0 = fmaf(P[O+0], t0, fmaf(P[O+1], t1, P[O+2] * t2));            \
        float s1 = fmaf(P[O+3], t0, fmaf(P[O+4], t1, P[O+5] * t2));            \
        float s2 = fmaf(P[O+6], t0, fmaf(P[O+7], t1, P[O+8] * t2));            \
        float g0 = P[O+12], g1 = P[O+13], g2 = P[O+14];                        \
        float q0 = tanh_fast(z0n), q1 = tanh_fast(z1n), q2 = tanh_fast(z2n);   \
        h0 = fmaf(g0, q0, z0n); h1 = fmaf(g1, q1, z1n); h2 = fmaf(g2, q2, z2n); \
        t0 = s0 * fmaf(g0, fmaf(-q0, q0, 1.f), 1.f);                           \
        t1 = s1 * fmaf(g1, fmaf(-q1, q1, 1.f), 1.f);                           \
        t2 = s2 * fmaf(g2, fmaf(-q2, q2, 1.f), 1.f);                           \
    }
    EB_LAYER(9)
    EB_LAYER(24)
    EB_LAYER(39)
#undef EB_LAYER

    float L = fmaf(P[54], h0, fmaf(P[55], h1, fmaf(P[56], h2, P[57])));
    float T = fmaf(P[54], t0, fmaf(P[55], t1, P[56] * t2));
    float Lc = fminf(fmaxf(L, -30.f), 30.f);
    float sg = rcp_fast(1.f + __expf(-Lc));
    float pdf = sg * (1.f - sg) * T;
    return __logf(pdf + 1e-9f);
}

// ---------------------------------------------------------------------------
// K0: block 0: prior params + u2^T.
//     blocks 1..100:   transpose ga/gac w1 into [100][128] zero-padded f32.
//     blocks 101..156: gs  w1 -> bf16 [112][128] zero-padded.
//     blocks 157..220: gsc w1 -> bf16 [128][128] zero-padded.
//     blocks 221..236: gsc w2 -> bf16 [32][128]  zero-padded.
// ---------------------------------------------------------------------------
__global__ __launch_bounds__(256) void k_prep(
    const float* __restrict__ H0p, const float* __restrict__ H1p,
    const float* __restrict__ H2p, const float* __restrict__ H3p,
    const float* __restrict__ H4p,
    const float* __restrict__ b0p, const float* __restrict__ b1p,
    const float* __restrict__ b2p, const float* __restrict__ b3p,
    const float* __restrict__ b4p,
    const float* __restrict__ a0p, const float* __restrict__ a1p,
    const float* __restrict__ a2p, const float* __restrict__ a3p,
    const float* __restrict__ u,
    const float* __restrict__ w1ga, const float* __restrict__ w1gac,
    const float* __restrict__ w1gs, const float* __restrict__ w1gsc,
    const float* __restrict__ w2gsc,
    float* __restrict__ eb, float* __restrict__ u2t,
    float* __restrict__ w1t, float* __restrict__ w1bfGS,
    float* __restrict__ w1bfGSC, float* __restrict__ w2bfGSC)
{
    int tid = threadIdx.x;
    if (blockIdx.x > 0) {
        int t = blockIdx.x - 1;
        if (t < 100) {
            int m = t / 50;
            int o = (t % 50) * 256 + tid;       // 0..12799
            int k = o >> 7, i = o & 127;
            const float* src = (m == 0) ? w1ga : w1gac;
            w1t[m * 12800 + o] = (i < 100) ? src[i * 100 + k] : 0.f;
        } else if (t < 156) {
            int o = (t - 100) * 256 + tid;      // 0..14335
            int i = o >> 7, k = o & 127;
            float v = (i < 100 && k < 100) ? w1gs[i * 100 + k] : 0.f;
            ((unsigned short*)w1bfGS)[o] = f2bf(v);
        } else if (t < 220) {
            int o = (t - 156) * 256 + tid;      // 0..16383
            int i = o >> 7, k = o & 127;
            float v = (i < 100 && k < 100) ? w1gsc[i * 100 + k] : 0.f;
            ((unsigned short*)w1bfGSC)[o] = f2bf(v);
        } else {
            int o = (t - 220) * 256 + tid;      // 0..4095
            int c = o >> 7, k = o & 127;
            float v = (c < 24 && k < 100) ? w2gsc[c * 100 + k] : 0.f;
            ((unsigned short*)w2bfGSC)[o] = f2bf(v);
        }
        return;
    }
    if (tid < 24) {
        int c = tid;
        float* P = eb + c * 58;
        for (int j = 0; j < 3; ++j) P[j]      = splus_precise(H0p[c*3+j]);
        for (int j = 0; j < 3; ++j) P[3+j]    = b0p[c*3+j];
        for (int j = 0; j < 3; ++j) P[6+j]    = tanhf(a0p[c*3+j]);
        for (int j = 0; j < 9; ++j) P[9+j]    = splus_precise(H1p[c*9+j]);
        for (int j = 0; j < 3; ++j) P[18+j]   = b1p[c*3+j];
        for (int j = 0; j < 3; ++j) P[21+j]   = tanhf(a1p[c*3+j]);
        for (int j = 0; j < 9; ++j) P[24+j]   = splus_precise(H2p[c*9+j]);
        for (int j = 0; j < 3; ++j) P[33+j]   = b2p[c*3+j];
        for (int j = 0; j < 3; ++j) P[36+j]   = tanhf(a2p[c*3+j]);
        for (int j = 0; j < 9; ++j) P[39+j]   = splus_precise(H3p[c*9+j]);
        for (int j = 0; j < 3; ++j) P[48+j]   = b3p[c*3+j];
        for (int j = 0; j < 3; ++j) P[51+j]   = tanhf(a3p[c*3+j]);
        for (int j = 0; j < 3; ++j) P[54+j]   = splus_precise(H4p[c*3+j]);
        P[57] = b4p[c];
    }
    int m = tid;
    if (m < 256) {
        for (int j = 0; j < 12; ++j) {
            float a  = u[m*24 + 2*j];
            float bb = u[m*24 + 2*j + 1];
            float p0 = fmaf(0.5f, bb, a);
            float p1 = 0.8660254037844386f * bb;
            float q0, q1; hexq(p0, p1, q0, q1);
            u2t[(2*j)   * 256 + m] = p0 - q0;
            u2t[(2*j+1) * 256 + m] = p1 - q1;
        }
    }
}

// ---------------------------------------------------------------------------
// gemm2 body v2 (vector f32, ga path which feeds hexq): 128 rows/block.
// ---------------------------------------------------------------------------
template <int MEAN>
__device__ __forceinline__ void gemm2_body(
    int bid,
    const float* __restrict__ in,
    const float* __restrict__ w0, const float* __restrict__ b0,
    const float* __restrict__ w1t,
    const float* __restrict__ b1, const float* __restrict__ w2,
    const float* __restrict__ b2,
    float* __restrict__ out, float* __restrict__ partial)
{
    __shared__ alignas(16) float shT[100 * 128];  // h0T [k][row]; reused as red
    __shared__ float S[128][2];

    int tid = threadIdx.x;
    int row0 = bid * 128;

    for (int e = tid; e < 12800; e += 256) {
        int j = e >> 7, row = e & 127;
        float2 xv = ((const float2*)in)[row0 + row];
        shT[j * 128 + row] =
            lrelu(fmaf(w0[2*j], xv.x, fmaf(w0[2*j+1], xv.y, b0[j])));
    }

    int rg = tid >> 4;        // rows 8rg..8rg+7
    int cg = tid & 15;        // cols 8cg..8cg+7 (of 128)
    __syncthreads();

    float4 acc0[8], acc1[8];
    float4 zero4 = make_float4(0.f, 0.f, 0.f, 0.f);
#pragma unroll
    for (int r = 0; r < 8; ++r) { acc0[r] = zero4; acc1[r] = zero4; }

    const float4* wg = (const float4*)w1t + cg * 2;
    const float4* hp = (const float4*)shT + rg * 2;
    float4 wa0 = wg[0],  wa1 = wg[1];
    float4 wb0 = wg[32], wb1 = wg[33];
#pragma unroll 2
    for (int k = 0; k < 100; ++k) {
        float4 wn0 = wg[(k + 2) * 32];
        float4 wn1 = wg[(k + 2) * 32 + 1];
        float4 ha = hp[k * 32];
        float4 hb = hp[k * 32 + 1];
        fma4(acc0[0], ha.x, wa0); fma4(acc1[0], ha.x, wa1);
        fma4(acc0[1], ha.y, wa0); fma4(acc1[1], ha.y, wa1);
        fma4(acc0[2], ha.z, wa0); fma4(acc1[2], ha.z, wa1);
        fma4(acc0[3], ha.w, wa0); fma4(acc1[3], ha.w, wa1);
        fma4(acc0[4], hb.x, wa0); fma4(acc1[4], hb.x, wa1);
        fma4(acc0[5], hb.y, wa0); fma4(acc1[5], hb.y, wa1);
        fma4(acc0[6], hb.z, wa0); fma4(acc1[6], hb.z, wa1);
        fma4(acc0[7], hb.w, wa0); fma4(acc1[7], hb.w, wa1);
        wa0 = wb0; wa1 = wb1; wb0 = wn0; wb1 = wn1;
    }
    __syncthreads();

    float b1v[8], w20v[8], w21v[8];
    int c0 = cg * 8;
#pragma unroll
    for (int e = 0; e < 8; ++e) {
        int c = c0 + e;
        bool v = (c < 100);
        b1v[e]  = v ? b1[c] : 0.f;
        w20v[e] = v ? w2[c] : 0.f;
        w21v[e] = v ? w2[100 + c] : 0.f;
    }
    float* red = shT;         // [128][2][16]
#pragma unroll
    for (int r = 0; r < 8; ++r) {
        float a0 = lrelu(acc0[r].x + b1v[0]);
        float a1 = lrelu(acc0[r].y + b1v[1]);
        float a2 = lrelu(acc0[r].z + b1v[2]);
        float a3 = lrelu(acc0[r].w + b1v[3]);
        float a4 = lrelu(acc1[r].x + b1v[4]);
        float a5 = lrelu(acc1[r].y + b1v[5]);
        float a6 = lrelu(acc1[r].z + b1v[6]);
        float a7 = lrelu(acc1[r].w + b1v[7]);
        float y0 = a0*w20v[0] + a1*w20v[1] + a2*w20v[2] + a3*w20v[3]
                 + a4*w20v[4] + a5*w20v[5] + a6*w20v[6] + a7*w20v[7];
        float y1 = a0*w21v[0] + a1*w21v[1] + a2*w21v[2] + a3*w21v[3]
                 + a4*w21v[4] + a5*w21v[5] + a6*w21v[6] + a7*w21v[7];
        int row = rg * 8 + r;
        red[(row * 2) * 16 + cg]     = y0;
        red[(row * 2 + 1) * 16 + cg] = y1;
    }
    __syncthreads();
    {
        int row = tid >> 1, p = tid & 1;
        const float4* rp = (const float4*)&red[(row * 2 + p) * 16];
        float4 v0 = rp[0], v1 = rp[1], v2 = rp[2], v3 = rp[3];
        float s = ((v0.x + v0.y) + (v0.z + v0.w))
                + ((v1.x + v1.y) + (v1.z + v1.w))
                + ((v2.x + v2.y) + (v2.z + v2.w))
                + ((v3.x + v3.y) + (v3.z + v3.w));
        float y = s + b2[p];
        out[(row0 + row) * 2 + p] = y;
        if (MEAN) S[row][p] = y;
    }
    if (MEAN) {
        __syncthreads();
        if (tid < 24) {
            int j = tid >> 1, par = tid & 1;
            int base = row0 % 12;
            int k0 = (j - base + 144) % 12;
            float s = 0.f;
            for (int k = k0; k < 128; k += 12) s += S[k][par];
            partial[bid * 24 + tid] = s;
        }
    }
}

// ---------------------------------------------------------------------------
// gs MFMA body (validated in R14): 64 rows/block, 4 waves x 16-row M-tiles.
// ---------------------------------------------------------------------------
__device__ __forceinline__ void gs_mfma_body(
    int bid,
    const float* __restrict__ in,
    const float* __restrict__ w0, const float* __restrict__ b0,
    const float* __restrict__ w1bf,
    const float* __restrict__ b1, const float* __restrict__ w2,
    const float* __restrict__ b2,
    float* __restrict__ out)
{
    int tid = threadIdx.x;
    int lane = tid & 63, wv = tid >> 6;
    int rsel = lane & 15;
    int kgrp = lane >> 4;
    int row0w = bid * 64 + wv * 16;

    float2 xv = ((const float2*)in)[row0w + rsel];

    bf16x8 afr[4];
#pragma unroll
    for (int kb = 0; kb < 4; ++kb) {
#pragma unroll
        for (int j8 = 0; j8 < 8; ++j8) {
            int j = kb * 32 + kgrp * 8 + j8;
            float h = 0.f;
            if (j < 100)
                h = lrelu(fmaf(w0[2*j], xv.x, fmaf(w0[2*j+1], xv.y, b0[j])));
            afr[kb][j8] = (short)f2bf(h);
        }
    }

    const unsigned short* w1u = (const unsigned short*)w1bf;
    f32x4 acc[7];
#pragma unroll
    for (int n = 0; n < 7; ++n) acc[n] = (f32x4){0.f, 0.f, 0.f, 0.f};
#pragma unroll
    for (int kb = 0; kb < 4; ++kb) {
#pragma unroll
        for (int n = 0; n < 7; ++n) {
            bf16x8 bfr = *(const bf16x8*)(w1u + (n * 16 + rsel) * 128
                                              + kb * 32 + kgrp * 8);
            acc[n] = __builtin_amdgcn_mfma_f32_16x16x32_bf16(afr[kb], bfr,
                                                             acc[n], 0, 0, 0);
        }
    }

    float py0[4] = {0.f, 0.f, 0.f, 0.f}, py1[4] = {0.f, 0.f, 0.f, 0.f};
#pragma unroll
    for (int n = 0; n < 7; ++n) {
        int i = n * 16 + rsel;
        bool v = (i < 100);
        float b1v = v ? b1[i] : 0.f;
        float w20 = v ? w2[i] : 0.f;
        float w21 = v ? w2[100 + i] : 0.f;
#pragma unroll
        for (int r = 0; r < 4; ++r) {
            float a = lrelu(acc[n][r] + b1v);
            py0[r] = fmaf(a, w20, py0[r]);
            py1[r] = fmaf(a, w21, py1[r]);
        }
    }
#pragma unroll
    for (int r = 0; r < 4; ++r) {
#pragma unroll
        for (int off = 1; off < 16; off <<= 1) {
            py0[r] += __shfl_xor(py0[r], off);
            py1[r] += __shfl_xor(py1[r], off);
        }
    }
    if (rsel == 0) {
#pragma unroll
        for (int r = 0; r < 4; ++r) {
            int row = row0w + kgrp * 4 + r;
            out[row * 2]     = py0[r] + b2[0];
            out[row * 2 + 1] = py1[r] + b2[1];
        }
    }
}

// ---------------------------------------------------------------------------
// K1: merged dispatch: blocks [0,384) = ga GEMM (y1 + mean partials),
// blocks [384, 384+384) = prior table build (4 v-slots per block).
// ---------------------------------------------------------------------------
__global__ __launch_bounds__(256, 2) void k_ga_table(
    const float* __restrict__ in,
    const float* __restrict__ w0, const float* __restrict__ b0,
    const float* __restrict__ w1t,
    const float* __restrict__ b1, const float* __restrict__ w2,
    const float* __restrict__ b2,
    float* __restrict__ out, float* __restrict__ partial,
    const float* __restrict__ eb, const float* __restrict__ u2t,
    float* __restrict__ tbl)
{
    if (blockIdx.x < (unsigned)GA_BLOCKS) {
        gemm2_body<1>(blockIdx.x, in, w0, b0, w1t, b1, w2, b2, out, partial);
    } else {
        int cv4 = blockIdx.x - GA_BLOCKS;      // 0..383
        int c = cv4 >> 4, vg = (cv4 & 15) * 4;
        int m = threadIdx.x;
        float step = (c & 1) ? STEP_ODD : 0.5f;
        float uv = u2t[c * 256 + m];
        const float* P = eb + c * 58;
#pragma unroll
        for (int dv = 0; dv < 4; ++dv) {
            int v = vg + dv;
            float val = (float)(KBASE + v) * step;
            tbl[(c * TBL_CAP + v) * 256 + m] = logpdf_ch(P, val + uv);
        }
    }
}

// ---------------------------------------------------------------------------
// K2: finish the EMA mean from 384 per-block partials (1 block, sub-us)
// ---------------------------------------------------------------------------
__global__ __launch_bounds__(256) void k_mean_final(
    const float* __restrict__ partial, const float* __restrict__ y_mean,
    float* __restrict__ ym)
{
    int tid = threadIdx.x;
    int c = tid >> 3, s = tid & 7;
    float v = 0.f;
    if (c < 24)
        for (int g = s; g < GA_BLOCKS; g += 8) v += partial[g * 24 + c];
    v += __shfl_xor(v, 1); v += __shfl_xor(v, 2); v += __shfl_xor(v, 4);
    if (c < 24 && s == 0)
        ym[c] = fmaf(0.05f, y_mean[c], 0.95f * (v * (1.0f / NB)));
}

// ---------------------------------------------------------------------------
// K3: gac only (f32, feeds hexq). 8 rows/block, 512 blocks.
// yhat = hexq(gac(y1 - ym)).
// ---------------------------------------------------------------------------
__global__ __launch_bounds__(256, 4) void k_gac(
    const float* __restrict__ y1,
    const float* __restrict__ w0A, const float* __restrict__ w1tA,
    const float* __restrict__ w2A,
    const float* __restrict__ ymg,
    float* __restrict__ yhat)
{
    __shared__ float sw0[2400];
    __shared__ float sw2[2400];
    __shared__ float sX[8 * 25];
    __shared__ float sO[8 * 25];
    __shared__ alignas(16) float h0[100 * 8];   // [j][r]
    __shared__ float h1[100 * 8];               // [i][r]
    __shared__ float symL[24];

    int tid = threadIdx.x;
    int row0 = blockIdx.x * 8;

    if (tid < 24) symL[tid] = ymg[tid];
    for (int t = tid; t < 2400; t += 256) {
        sw0[t] = w0A[t];
        sw2[t] = w2A[t];
    }
    __syncthreads();
    for (int e = tid; e < 192; e += 256) {
        int r = e / 24, c = e - r * 24;
        sX[r * 25 + c] = y1[row0 * 24 + e] - symL[c];
    }
    __syncthreads();

    int ii = tid & 127, rg = tid >> 7;

    // layer 0
    for (int e = tid; e < 800; e += 256) {
        int j = e >> 3, r = e & 7;
        const float* wr = sw0 + j * 24;
        const float* xr = sX + r * 25;
        float a = 0.f, b = 0.f;
#pragma unroll
        for (int k = 0; k < 24; k += 2) {
            a = fmaf(wr[k],     xr[k],     a);
            b = fmaf(wr[k + 1], xr[k + 1], b);
        }
        h0[j * 8 + r] = splus(a + b);
    }
    __syncthreads();

    // layer 1 (w1t column-coalesced from L2)
    {
        float4 a = make_float4(0.f, 0.f, 0.f, 0.f);
        const float* wc = w1tA + ii;
        const float4* h4 = (const float4*)h0 + rg;
#pragma unroll 4
        for (int j = 0; j < 100; ++j) {
            float w = wc[j * 128];
            float4 h = h4[j * 2];
            a.x = fmaf(w, h.x, a.x); a.y = fmaf(w, h.y, a.y);
            a.z = fmaf(w, h.z, a.z); a.w = fmaf(w, h.w, a.w);
        }
        if (ii < 100) {
            h1[ii * 8 + rg * 4]     = splus(a.x);
            h1[ii * 8 + rg * 4 + 1] = splus(a.y);
            h1[ii * 8 + rg * 4 + 2] = splus(a.z);
            h1[ii * 8 + rg * 4 + 3] = splus(a.w);
        }
    }
    __syncthreads();

    // layer 2
    if (tid < 192) {
        int c = tid >> 3, r = tid & 7;
        const float* w2r = sw2 + c * 100;
        float s = 0.f, s2 = 0.f;
#pragma unroll 4
        for (int i = 0; i < 100; i += 2) {
            s  = fmaf(w2r[i],     h1[i * 8 + r],       s);
            s2 = fmaf(w2r[i + 1], h1[(i + 1) * 8 + r], s2);
        }
        sO[r * 25 + c] = s + s2;
    }
    __syncthreads();
    if (tid < 96) {
        int pr = tid >> 3, r = tid & 7;
        float v0 = sO[r * 25 + 2*pr], v1 = sO[r * 25 + 2*pr + 1];
        float q0, q1; hexq(v0, v1, q0, q1);
        yhat[(row0 + r) * 24 + 2*pr]     = q0;
        yhat[(row0 + r) * 24 + 2*pr + 1] = q1;
    }
}

// ---------------------------------------------------------------------------
// K4: gsc MFMA v3 (spill-free): LDS-staged w0 and input rows; layer-1 split
// into two 4-N-tile passes (max live regs ~60). 64 rows/block, 4 waves.
// ---------------------------------------------------------------------------
__global__ __launch_bounds__(256, 2) void k_gsc(
    const float* __restrict__ yhat,
    const float* __restrict__ w0,
    const float* __restrict__ w1bfC, const float* __restrict__ w2bfC,
    const float* __restrict__ ymg, float* __restrict__ yhat1)
{
    __shared__ float sw0[2400];               // 9.6 KB
    __shared__ float sX[64 * 24];             // 6 KB
    __shared__ float h1L[4 * 128 * 16];       // 32 KB

    int tid = threadIdx.x;
    int lane = tid & 63, wv = tid >> 6;
    int rsel = lane & 15;
    int kgrp = lane >> 4;
    int row0 = blockIdx.x * 64;
    int row0w = row0 + wv * 16;

    for (int t = tid; t < 2400; t += 256) sw0[t] = w0[t];
    for (int t = tid; t < 1536; t += 256) sX[t] = yhat[row0 * 24 + t];
    __syncthreads();

    const float* xr = sX + (wv * 16 + rsel) * 24;

    // layer 0 (f32, inputs/weights from LDS) -> A fragments
    bf16x8 afr[4];
#pragma unroll
    for (int kb = 0; kb < 4; ++kb) {
#pragma unroll
        for (int j8 = 0; j8 < 8; ++j8) {
            int j = kb * 32 + kgrp * 8 + j8;
            float h = 0.f;
            if (j < 100) {
                const float* wr = sw0 + j * 24;
                float a = 0.f, b = 0.f;
#pragma unroll
                for (int k = 0; k < 24; k += 2) {
                    a = fmaf(wr[k],     xr[k],     a);
                    b = fmaf(wr[k + 1], xr[k + 1], b);
                }
                h = splus(a + b);
            }
            afr[kb][j8] = (short)f2bf(h);
        }
    }

    // layer 1: two passes of 4 N-tiles (acc live = 16 VGPRs per pass)
    const unsigned short* w1u = (const unsigned short*)w1bfC;
    float* hl = h1L + wv * 128 * 16;
#pragma unroll 1
    for (int half = 0; half < 2; ++half) {
        f32x4 acc[4];
#pragma unroll
        for (int n = 0; n < 4; ++n) acc[n] = (f32x4){0.f, 0.f, 0.f, 0.f};
#pragma unroll
        for (int kb = 0; kb < 4; ++kb) {
#pragma unroll
            for (int n = 0; n < 4; ++n) {
                int nt = half * 4 + n;
                bf16x8 bfr = *(const bf16x8*)(w1u + (nt * 16 + rsel) * 128
                                                  + kb * 32 + kgrp * 8);
                acc[n] = __builtin_amdgcn_mfma_f32_16x16x32_bf16(afr[kb], bfr,
                                                                 acc[n], 0, 0, 0);
            }
        }
#pragma unroll
        for (int n = 0; n < 4; ++n) {
            int i = (half * 4 + n) * 16 + rsel;
            float v0 = (i < 100) ? splus(acc[n][0]) : 0.f;
            float v1 = (i < 100) ? splus(acc[n][1]) : 0.f;
            float v2 = (i < 100) ? splus(acc[n][2]) : 0.f;
            float v3 = (i < 100) ? splus(acc[n][3]) : 0.f;
            hl[i * 16 + kgrp * 4]     = v0;
            hl[i * 16 + kgrp * 4 + 1] = v1;
            hl[i * 16 + kgrp * 4 + 2] = v2;
            hl[i * 16 + kgrp * 4 + 3] = v3;
        }
    }
    __syncthreads();

    // layer 2: A-frags built per K-block from LDS, 2 N-tiles
    const unsigned short* w2u = (const unsigned short*)w2bfC;
    f32x4 acc2[2];
    acc2[0] = (f32x4){0.f, 0.f, 0.f, 0.f};
    acc2[1] = (f32x4){0.f, 0.f, 0.f, 0.f};
#pragma unroll 1
    for (int kb = 0; kb < 4; ++kb) {
        bf16x8 afr2;
#pragma unroll
        for (int j8 = 0; j8 < 8; ++j8) {
            int i = kb * 32 + kgrp * 8 + j8;
            afr2[j8] = (short)f2bf(hl[i * 16 + rsel]);
        }
#pragma unroll
        for (int n = 0; n < 2; ++n) {
            bf16x8 bfr = *(const bf16x8*)(w2u + (n * 16 + rsel) * 128
                                              + kb * 32 + kgrp * 8);
            acc2[n] = __builtin_amdgcn_mfma_f32_16x16x32_bf16(afr2, bfr,
                                                              acc2[n], 0, 0, 0);
        }
    }

#pragma unroll
    for (int n = 0; n < 2; ++n) {
        int c = n * 16 + rsel;
        if (c < 24) {
            float ym = ymg[c];
#pragma unroll
            for (int r = 0; r < 4; ++r)
                yhat1[(row0w + kgrp * 4 + r) * 24 + c] = acc2[n][r] + ym;
        }
    }
}

// ---------------------------------------------------------------------------
// K5 (merged, R14-validated): blocks [0,768) = gs MFMA -> xhat;
// blocks [768,768+1024) = MC likelihood (4 rows/block, clamped gathers).
// ---------------------------------------------------------------------------
__global__ __launch_bounds__(256, 4) void k_gs_mc(
    const float* __restrict__ yhat1,
    const float* __restrict__ w0, const float* __restrict__ b0,
    const float* __restrict__ w1bf,
    const float* __restrict__ b1, const float* __restrict__ w2,
    const float* __restrict__ b2, float* __restrict__ xhat,
    const float* __restrict__ yhat, const float* __restrict__ u2t,
    const float* __restrict__ eb,
    const float* __restrict__ tbl, float* __restrict__ lik)
{
    if (blockIdx.x < (unsigned)GS_BLOCKS) {
        gs_mfma_body(blockIdx.x, yhat1, w0, b0, w1bf, b1, w2, b2, xhat);
        return;
    }
    __shared__ float sy[4 * 24];
    __shared__ float redm[4], reds[4];
    int tid = threadIdx.x;
    int wv = tid >> 6;
    int bg = (blockIdx.x - GS_BLOCKS) * 4;

    if (tid < 96) sy[tid] = yhat[bg * 24 + tid];
    __syncthreads();

    for (int q = 0; q < 4; ++q) {
        float lp = 0.f;
        unsigned miss = 0;
#pragma unroll
        for (int c = 0; c < 24; ++c) {
            float yv = sy[q * 24 + c];
            float inv = (c & 1) ? INV_ODD : 2.0f;
            int k = (int)rintf(yv * inv);
            int idx = k - KBASE;
            bool ok = (idx >= 0 && idx < TBL_CAP);
            int idq = min(max(idx, 0), TBL_CAP - 1);
            float tv = tbl[(c * TBL_CAP + idq) * 256 + tid];  // unconditional
            lp += ok ? tv : 0.f;
            if (!ok) miss |= (1u << c);
        }
        while (miss) {
            int c = __ffs(miss) - 1;
            miss &= miss - 1;
            lp += logpdf_ch(eb + c * 58, sy[q * 24 + c] + u2t[c * 256 + tid]);
        }

        float m = lp;
#pragma unroll
        for (int off = 1; off < 64; off <<= 1) m = fmaxf(m, __shfl_xor(m, off));
        if ((tid & 63) == 0) redm[wv] = m;
        __syncthreads();
        float mx = fmaxf(fmaxf(redm[0], redm[1]), fmaxf(redm[2], redm[3]));
        float e = __expf(lp - mx);
#pragma unroll
        for (int off = 1; off < 64; off <<= 1) e += __shfl_xor(e, off);
        if ((tid & 63) == 0) reds[wv] = e;
        __syncthreads();
        if (tid == 0)
            lik[bg + q] = mx + __logf(reds[0] + reds[1] + reds[2] + reds[3])
                        - 7.271269879190247f;  // -log(NMC) + LOG_VOL
        __syncthreads();
    }
}

// ---------------------------------------------------------------------------
// Fallback MC (ws too small for the table)
// ---------------------------------------------------------------------------
__global__ __launch_bounds__(256) void k_mc_direct(
    const float* __restrict__ yhat, const float* __restrict__ u2t,
    const float* __restrict__ eb, float* __restrict__ lik)
{
    __shared__ alignas(16) float sU[24 * 256];
    __shared__ float redm[4], reds[4];
    int tid = threadIdx.x;
    int wv = tid >> 6;
    int b = blockIdx.x;
    for (int i = tid; i < 1536; i += 256)
        ((float4*)sU)[i] = ((const float4*)u2t)[i];
    __syncthreads();

    float lp = 0.f;
    for (int c = 0; c < 24; ++c)
        lp += logpdf_ch(eb + c * 58, yhat[b * 24 + c] + sU[c * 256 + tid]);

    float m = lp;
#pragma unroll
    for (int off = 1; off < 64; off <<= 1) m = fmaxf(m, __shfl_xor(m, off));
    if ((tid & 63) == 0) redm[wv] = m;
    __syncthreads();
    float mx = fmaxf(fmaxf(redm[0], redm[1]), fmaxf(redm[2], redm[3]));
    float e = __expf(lp - mx);
#pragma unroll
    for (int off = 1; off < 64; off <<= 1) e += __shfl_xor(e, off);
    if ((tid & 63) == 0) reds[wv] = e;
    __syncthreads();
    if (tid == 0)
        lik[b] = mx + __logf(reds[0] + reds[1] + reds[2] + reds[3])
               - 7.271269879190247f;
}

__global__ __launch_bounds__(256, 4) void k_gs_only(
    const float* __restrict__ yhat1,
    const float* __restrict__ w0, const float* __restrict__ b0,
    const float* __restrict__ w1bf,
    const float* __restrict__ b1, const float* __restrict__ w2,
    const float* __restrict__ b2, float* __restrict__ xhat)
{
    gs_mfma_body(blockIdx.x, yhat1, w0, b0, w1bf, b1, w2, b2, xhat);
}

// ---------------------------------------------------------------------------
extern "C" void kernel_launch(void* const* d_in, const int* in_sizes, int n_in,
                              void* d_out, int out_size, void* d_ws, size_t ws_size,
                              hipStream_t stream)
{
    (void)in_sizes; (void)n_in; (void)out_size;
    const float* x      = (const float*)d_in[0];
    const float* y_mean = (const float*)d_in[1];
    const float* u      = (const float*)d_in[2];
    const float* ga_w0  = (const float*)d_in[3];
    const float* ga_b0  = (const float*)d_in[4];
    const float* ga_w1  = (const float*)d_in[5];
    const float* ga_b1  = (const float*)d_in[6];
    const float* ga_w2  = (const float*)d_in[7];
    const float* ga_b2  = (const float*)d_in[8];
    const float* gs_w0  = (const float*)d_in[9];
    const float* gs_b0  = (const float*)d_in[10];
    const float* gs_w1  = (const float*)d_in[11];
    const float* gs_b1  = (const float*)d_in[12];
    const float* gs_w2  = (const float*)d_in[13];
    const float* gs_b2  = (const float*)d_in[14];
    const float* gac_w0 = (const float*)d_in[15];
    const float* gac_w1 = (const float*)d_in[16];
    const float* gac_w2 = (const float*)d_in[17];
    const float* gsc_w0 = (const float*)d_in[18];
    const float* gsc_w1 = (const float*)d_in[19];
    const float* gsc_w2 = (const float*)d_in[20];
    const float* eb_H0  = (const float*)d_in[21];
    const float* eb_H1  = (const float*)d_in[22];
    const float* eb_H2  = (const float*)d_in[23];
    const float* eb_H3  = (const float*)d_in[24];
    const float* eb_H4  = (const float*)d_in[25];
    const float* eb_b0  = (const float*)d_in[26];
    const float* eb_b1  = (const float*)d_in[27];
    const float* eb_b2  = (const float*)d_in[28];
    const float* eb_b3  = (const float*)d_in[29];
    const float* eb_b4  = (const float*)d_in[30];
    const float* eb_a0  = (const float*)d_in[31];
    const float* eb_a1  = (const float*)d_in[32];
    const float* eb_a2  = (const float*)d_in[33];
    const float* eb_a3  = (const float*)d_in[34];

    float* ws    = (float*)d_ws;
    float* y1    = ws + WS_Y1;
    float* yhat  = ws + WS_YHAT;
    float* yhat1 = ws + WS_YHAT1;
    float* ym    = ws + WS_YM;
    float* u2t   = ws + WS_U2T;
    float* eb    = ws + WS_EB;
    float* part  = ws + WS_PART;
    float* w1t   = ws + WS_W1T;
    float* w1bfGS  = ws + WS_W1BFGS;
    float* w1bfGSC = ws + WS_W1BFGSC;
    float* w2bfGSC = ws + WS_W2BFGSC;
    float* tbl   = ws + WS_TBL;
    float* xhat  = (float*)d_out;
    float* lik   = (float*)d_out + 98304;

    float* w1tGA  = w1t;
    float* w1tGAC = w1t + 12800;

    bool use_tbl = ws_size >= WS_END * sizeof(float);

    k_prep<<<237, 256, 0, stream>>>(eb_H0, eb_H1, eb_H2, eb_H3, eb_H4,
                                    eb_b0, eb_b1, eb_b2, eb_b3, eb_b4,
                                    eb_a0, eb_a1, eb_a2, eb_a3, u,
                                    ga_w1, gac_w1, gs_w1, gsc_w1, gsc_w2,
                                    eb, u2t, w1t, w1bfGS, w1bfGSC, w2bfGSC);
    if (use_tbl)
        k_ga_table<<<GA_BLOCKS + 24 * TBL_CAP / 4, 256, 0, stream>>>(
            x, ga_w0, ga_b0, w1tGA, ga_b1, ga_w2, ga_b2, y1, part,
            eb, u2t, tbl);
    else
        k_ga_table<<<GA_BLOCKS, 256, 0, stream>>>(
            x, ga_w0, ga_b0, w1tGA, ga_b1, ga_w2, ga_b2, y1, part,
            eb, u2t, tbl);
    k_mean_final<<<1, 256, 0, stream>>>(part, y_mean, ym);
    k_gac<<<NB / 8, 256, 0, stream>>>(y1, gac_w0, w1tGAC, gac_w2, ym, yhat);
    k_gsc<<<GSC_BLOCKS, 256, 0, stream>>>(yhat, gsc_w0, w1bfGSC, w2bfGSC,
                                          ym, yhat1);
    if (use_tbl) {
        k_gs_mc<<<GS_BLOCKS + NB / 4, 256, 0, stream>>>(
            yhat1, gs_w0, gs_b0, w1bfGS, gs_b1, gs_w2, gs_b2, xhat,
            yhat, u2t, eb, tbl, lik);
    } else {
        k_gs_only<<<GS_BLOCKS, 256, 0, stream>>>(
            yhat1, gs_w0, gs_b0, w1bfGS, gs_b1, gs_w2, gs_b2, xhat);
        k_mc_direct<<<NB, 256, 0, stream>>>(yhat, u2t, eb, lik);
    }
}

// Round 18
// 113.506 us; speedup vs baseline: 1.4723x; 1.2532x over previous
//
#include <hip/hip_runtime.h>
#include <hip/hip_bf16.h>
#include <math.h>
#include <limits.h>

// Problem dims
constexpr int NB    = 4096;   // batch
constexpr int ROWS2 = NB * 12;            // 49152 rows for the 2->100->100->2 MLPs
constexpr int GA_BLOCKS = ROWS2 / 128;    // 384 (128 rows/block, vector path)
constexpr int GS_BLOCKS = ROWS2 / 64;     // 768 (64 rows/block, MFMA path)
constexpr int TBL_CAP = 64;               // lattice slots per channel (fixed range)
constexpr int KBASE   = -32;              // fixed kmin for all channels

// workspace layout (float offsets)
constexpr size_t WS_Y1    = 0;              // NB*24
constexpr size_t WS_YHAT  = 98304;          // NB*24
constexpr size_t WS_YHAT1 = 196608;         // NB*24
constexpr size_t WS_YM    = 294912;         // 24
constexpr size_t WS_U2T   = 294936;         // 24*256 (transposed: [c][m])
constexpr size_t WS_EB    = 301080;         // 24*58 precomputed prior params
constexpr size_t WS_PART  = 302472;         // per-block mean partials
constexpr size_t WS_W1T   = 320904;         // 3 x [100][128] transposed w1 (ga,gac,gsc)
constexpr size_t WS_W1BF  = 359304;         // gs w1 as bf16 [112][128] (7168 floats)
constexpr size_t WS_TBL   = 366472;         // 24*64*256 table of log(pdf+1e-9)
constexpr size_t WS_END   = WS_TBL + 24 * TBL_CAP * 256;   // 759688 floats (~3.04 MB)

constexpr float STEP_ODD = 0.8660254037844386f;   // sqrt(3)/2
constexpr float INV_ODD  = 1.1547005383792517f;   // 2/sqrt(3)

typedef __attribute__((ext_vector_type(8))) short bf16x8;
typedef __attribute__((ext_vector_type(4))) float f32x4;

__device__ __forceinline__ float lrelu(float x) { return x >= 0.f ? x : 0.01f * x; }
__device__ __forceinline__ float rcp_fast(float x) { return __builtin_amdgcn_rcpf(x); }

__device__ __forceinline__ unsigned short f2bf(float f) {   // RNE f32 -> bf16
    unsigned b = __float_as_uint(f);
    b += 0x7FFFu + ((b >> 16) & 1u);
    return (unsigned short)(b >> 16);
}

__device__ __forceinline__ float tanh_fast(float x) {
    float xx = fminf(fmaxf(x, -15.f), 15.f);
    float e = __expf(xx + xx);
    return fmaf(-2.f, rcp_fast(e + 1.f), 1.f);
}
__device__ __forceinline__ float splus(float x) {
    return fmaxf(x, 0.f) + __logf(1.f + __expf(-fabsf(x)));
}
__device__ __forceinline__ float splus_precise(float x) {
    return fmaxf(x, 0.f) + log1pf(expf(-fabsf(x)));
}

__device__ __forceinline__ void fma4(float4& a, float h, const float4& w) {
    a.x = fmaf(h, w.x, a.x); a.y = fmaf(h, w.y, a.y);
    a.z = fmaf(h, w.z, a.z); a.w = fmaf(h, w.w, a.w);
}

// exact A2 hex lattice nearest-point quantizer; matches jnp.round (rint = RNE)
__device__ __forceinline__ void hexq(float p0, float p1, float& q0, float& q1) {
    const float S3 = 1.7320508075688772f;
    const float H3 = 0.8660254037844386f;
    float c00 = rintf(p0);
    float c01 = rintf(p1 / S3) * S3;
    float c10 = rintf(p0 - 0.5f) + 0.5f;
    float c11 = rintf((p1 - H3) / S3) * S3 + H3;
    float d0 = (p0 - c00) * (p0 - c00) + (p1 - c01) * (p1 - c01);
    float d1 = (p0 - c10) * (p0 - c10) + (p1 - c11) * (p1 - c11);
    bool take0 = d0 <= d1;
    q0 = take0 ? c00 : c10;
    q1 = take0 ? c01 : c11;
}

// per-channel prior chain: log(pdf + 1e-9) at point p, params P (58 floats)
__device__ __forceinline__ float logpdf_ch(const float* __restrict__ P, float p) {
    float w00 = P[0], w01 = P[1], w02 = P[2];
    float z0 = fmaf(w00, p, P[3]);
    float z1 = fmaf(w01, p, P[4]);
    float z2 = fmaf(w02, p, P[5]);
    float a0 = P[6], a1 = P[7], a2 = P[8];
    float e0 = tanh_fast(z0), e1 = tanh_fast(z1), e2 = tanh_fast(z2);
    float h0 = fmaf(a0, e0, z0), h1 = fmaf(a1, e1, z1), h2 = fmaf(a2, e2, z2);
    float t0 = w00 * fmaf(a0, fmaf(-e0, e0, 1.f), 1.f);
    float t1 = w01 * fmaf(a1, fmaf(-e1, e1, 1.f), 1.f);
    float t2 = w02 * fmaf(a2, fmaf(-e2, e2, 1.f), 1.f);

#define EB_LAYER(O)                                                            \
    {                                                                          \
        float z0n = fmaf(P[O+0], h0, fmaf(P[O+1], h1, fmaf(P[O+2], h2, P[O+9])));  \
        float z1n = fmaf(P[O+3], h0, fmaf(P[O+4], h1, fmaf(P[O+5], h2, P[O+10]))); \
        float z2n = fmaf(P[O+6], h0, fmaf(P[O+7], h1, fmaf(P[O+8], h2, P[O+11]))); \
        float s0 = fmaf(P[O+0], t0, fmaf(P[O+1], t1, P[O+2] * t2));            \
        float s1 = fmaf(P[O+3], t0, fmaf(P[O+4], t1, P[O+5] * t2));            \
        float s2 = fmaf(P[O+6], t0, fmaf(P[O+7], t1, P[O+8] * t2));            \
        float g0 = P[O+12], g1 = P[O+13], g2 = P[O+14];                        \
        float q0 = tanh_fast(z0n), q1 = tanh_fast(z1n), q2 = tanh_fast(z2n);   \
        h0 = fmaf(g0, q0, z0n); h1 = fmaf(g1, q1, z1n); h2 = fmaf(g2, q2, z2n); \
        t0 = s0 * fmaf(g0, fmaf(-q0, q0, 1.f), 1.f);                           \
        t1 = s1 * fmaf(g1, fmaf(-q1, q1, 1.f), 1.f);                           \
        t2 = s2 * fmaf(g2, fmaf(-q2, q2, 1.f), 1.f);                           \
    }
    EB_LAYER(9)
    EB_LAYER(24)
    EB_LAYER(39)
#undef EB_LAYER

    float L = fmaf(P[54], h0, fmaf(P[55], h1, fmaf(P[56], h2, P[57])));
    float T = fmaf(P[54], t0, fmaf(P[55], t1, P[56] * t2));
    float Lc = fminf(fmaxf(L, -30.f), 30.f);
    float sg = rcp_fast(1.f + __expf(-Lc));
    float pdf = sg * (1.f - sg) * T;
    return __logf(pdf + 1e-9f);
}

// ---------------------------------------------------------------------------
// K0: block 0: prior params + u2^T.
//     blocks 1..150: transpose ga/gac/gsc w1 into [100][128] zero-padded f32.
//     blocks 151..206: convert gs w1 to bf16 [112][128] zero-padded.
// ---------------------------------------------------------------------------
__global__ __launch_bounds__(256) void k_prep(
    const float* __restrict__ H0p, const float* __restrict__ H1p,
    const float* __restrict__ H2p, const float* __restrict__ H3p,
    const float* __restrict__ H4p,
    const float* __restrict__ b0p, const float* __restrict__ b1p,
    const float* __restrict__ b2p, const float* __restrict__ b3p,
    const float* __restrict__ b4p,
    const float* __restrict__ a0p, const float* __restrict__ a1p,
    const float* __restrict__ a2p, const float* __restrict__ a3p,
    const float* __restrict__ u,
    const float* __restrict__ w1ga, const float* __restrict__ w1gac,
    const float* __restrict__ w1gsc, const float* __restrict__ w1gs,
    float* __restrict__ eb, float* __restrict__ u2t,
    float* __restrict__ w1t, float* __restrict__ w1bf)
{
    int tid = threadIdx.x;
    if (blockIdx.x > 0) {
        int t = blockIdx.x - 1;
        if (t < 150) {
            int m = t / 50;
            int o = (t % 50) * 256 + tid;       // 0..12799
            int k = o >> 7, i = o & 127;
            const float* src = (m == 0) ? w1ga : (m == 1) ? w1gac : w1gsc;
            w1t[m * 12800 + o] = (i < 100) ? src[i * 100 + k] : 0.f;
        } else {
            int o = (t - 150) * 256 + tid;      // 0..14335
            int i = o >> 7, k = o & 127;
            float v = (i < 100 && k < 100) ? w1gs[i * 100 + k] : 0.f;
            ((unsigned short*)w1bf)[o] = f2bf(v);
        }
        return;
    }
    if (tid < 24) {
        int c = tid;
        float* P = eb + c * 58;
        for (int j = 0; j < 3; ++j) P[j]      = splus_precise(H0p[c*3+j]);
        for (int j = 0; j < 3; ++j) P[3+j]    = b0p[c*3+j];
        for (int j = 0; j < 3; ++j) P[6+j]    = tanhf(a0p[c*3+j]);
        for (int j = 0; j < 9; ++j) P[9+j]    = splus_precise(H1p[c*9+j]);
        for (int j = 0; j < 3; ++j) P[18+j]   = b1p[c*3+j];
        for (int j = 0; j < 3; ++j) P[21+j]   = tanhf(a1p[c*3+j]);
        for (int j = 0; j < 9; ++j) P[24+j]   = splus_precise(H2p[c*9+j]);
        for (int j = 0; j < 3; ++j) P[33+j]   = b2p[c*3+j];
        for (int j = 0; j < 3; ++j) P[36+j]   = tanhf(a2p[c*3+j]);
        for (int j = 0; j < 9; ++j) P[39+j]   = splus_precise(H3p[c*9+j]);
        for (int j = 0; j < 3; ++j) P[48+j]   = b3p[c*3+j];
        for (int j = 0; j < 3; ++j) P[51+j]   = tanhf(a3p[c*3+j]);
        for (int j = 0; j < 3; ++j) P[54+j]   = splus_precise(H4p[c*3+j]);
        P[57] = b4p[c];
    }
    int m = tid;
    if (m < 256) {
        for (int j = 0; j < 12; ++j) {
            float a  = u[m*24 + 2*j];
            float bb = u[m*24 + 2*j + 1];
            float p0 = fmaf(0.5f, bb, a);
            float p1 = 0.8660254037844386f * bb;
            float q0, q1; hexq(p0, p1, q0, q1);
            u2t[(2*j)   * 256 + m] = p0 - q0;
            u2t[(2*j+1) * 256 + m] = p1 - q1;
        }
    }
}

// ---------------------------------------------------------------------------
// gemm2 body v2 (vector f32, for the ga path which feeds hexq):
// 128 rows/block, 256 threads, thread tile 8 rows x 8 cols.
// ---------------------------------------------------------------------------
template <int MEAN>
__device__ __forceinline__ void gemm2_body(
    int bid,
    const float* __restrict__ in,
    const float* __restrict__ w0, const float* __restrict__ b0,
    const float* __restrict__ w1t,
    const float* __restrict__ b1, const float* __restrict__ w2,
    const float* __restrict__ b2,
    float* __restrict__ out, float* __restrict__ partial)
{
    __shared__ alignas(16) float shT[100 * 128];  // h0T [k][row]; reused as red
    __shared__ float S[128][2];

    int tid = threadIdx.x;
    int row0 = bid * 128;

    for (int e = tid; e < 12800; e += 256) {
        int j = e >> 7, row = e & 127;
        float2 xv = ((const float2*)in)[row0 + row];
        shT[j * 128 + row] =
            lrelu(fmaf(w0[2*j], xv.x, fmaf(w0[2*j+1], xv.y, b0[j])));
    }

    int rg = tid >> 4;        // rows 8rg..8rg+7
    int cg = tid & 15;        // cols 8cg..8cg+7 (of 128)
    __syncthreads();

    float4 acc0[8], acc1[8];
    float4 zero4 = make_float4(0.f, 0.f, 0.f, 0.f);
#pragma unroll
    for (int r = 0; r < 8; ++r) { acc0[r] = zero4; acc1[r] = zero4; }

    const float4* wg = (const float4*)w1t + cg * 2;
    const float4* hp = (const float4*)shT + rg * 2;
    float4 wa0 = wg[0],  wa1 = wg[1];
    float4 wb0 = wg[32], wb1 = wg[33];
#pragma unroll 2
    for (int k = 0; k < 100; ++k) {
        float4 wn0 = wg[(k + 2) * 32];
        float4 wn1 = wg[(k + 2) * 32 + 1];
        float4 ha = hp[k * 32];
        float4 hb = hp[k * 32 + 1];
        fma4(acc0[0], ha.x, wa0); fma4(acc1[0], ha.x, wa1);
        fma4(acc0[1], ha.y, wa0); fma4(acc1[1], ha.y, wa1);
        fma4(acc0[2], ha.z, wa0); fma4(acc1[2], ha.z, wa1);
        fma4(acc0[3], ha.w, wa0); fma4(acc1[3], ha.w, wa1);
        fma4(acc0[4], hb.x, wa0); fma4(acc1[4], hb.x, wa1);
        fma4(acc0[5], hb.y, wa0); fma4(acc1[5], hb.y, wa1);
        fma4(acc0[6], hb.z, wa0); fma4(acc1[6], hb.z, wa1);
        fma4(acc0[7], hb.w, wa0); fma4(acc1[7], hb.w, wa1);
        wa0 = wb0; wa1 = wb1; wb0 = wn0; wb1 = wn1;
    }
    __syncthreads();

    float b1v[8], w20v[8], w21v[8];
    int c0 = cg * 8;
#pragma unroll
    for (int e = 0; e < 8; ++e) {
        int c = c0 + e;
        bool v = (c < 100);
        b1v[e]  = v ? b1[c] : 0.f;
        w20v[e] = v ? w2[c] : 0.f;
        w21v[e] = v ? w2[100 + c] : 0.f;
    }
    float* red = shT;         // [128][2][16]
#pragma unroll
    for (int r = 0; r < 8; ++r) {
        float a0 = lrelu(acc0[r].x + b1v[0]);
        float a1 = lrelu(acc0[r].y + b1v[1]);
        float a2 = lrelu(acc0[r].z + b1v[2]);
        float a3 = lrelu(acc0[r].w + b1v[3]);
        float a4 = lrelu(acc1[r].x + b1v[4]);
        float a5 = lrelu(acc1[r].y + b1v[5]);
        float a6 = lrelu(acc1[r].z + b1v[6]);
        float a7 = lrelu(acc1[r].w + b1v[7]);
        float y0 = a0*w20v[0] + a1*w20v[1] + a2*w20v[2] + a3*w20v[3]
                 + a4*w20v[4] + a5*w20v[5] + a6*w20v[6] + a7*w20v[7];
        float y1 = a0*w21v[0] + a1*w21v[1] + a2*w21v[2] + a3*w21v[3]
                 + a4*w21v[4] + a5*w21v[5] + a6*w21v[6] + a7*w21v[7];
        int row = rg * 8 + r;
        red[(row * 2) * 16 + cg]     = y0;
        red[(row * 2 + 1) * 16 + cg] = y1;
    }
    __syncthreads();
    {
        int row = tid >> 1, p = tid & 1;
        const float4* rp = (const float4*)&red[(row * 2 + p) * 16];
        float4 v0 = rp[0], v1 = rp[1], v2 = rp[2], v3 = rp[3];
        float s = ((v0.x + v0.y) + (v0.z + v0.w))
                + ((v1.x + v1.y) + (v1.z + v1.w))
                + ((v2.x + v2.y) + (v2.z + v2.w))
                + ((v3.x + v3.y) + (v3.z + v3.w));
        float y = s + b2[p];
        out[(row0 + row) * 2 + p] = y;
        if (MEAN) S[row][p] = y;
    }
    if (MEAN) {
        __syncthreads();
        if (tid < 24) {
            int j = tid >> 1, par = tid & 1;
            int base = row0 % 12;
            int k0 = (j - base + 144) % 12;
            float s = 0.f;
            for (int k = k0; k < 128; k += 12) s += S[k][par];
            partial[bid * 24 + tid] = s;
        }
    }
}

// ---------------------------------------------------------------------------
// gs MFMA body (bf16 matrix cores; post-quantization path, bf16-safe).
// 64 rows/block, 4 waves; wave w owns M-tile rows bid*64+w*16..+15.
// ---------------------------------------------------------------------------
__device__ __forceinline__ void gs_mfma_body(
    int bid,
    const float* __restrict__ in,
    const float* __restrict__ w0, const float* __restrict__ b0,
    const float* __restrict__ w1bf,
    const float* __restrict__ b1, const float* __restrict__ w2,
    const float* __restrict__ b2,
    float* __restrict__ out)
{
    int tid = threadIdx.x;
    int lane = tid & 63, wv = tid >> 6;
    int rsel = lane & 15;     // A row within tile / D col (i within N-tile)
    int kgrp = lane >> 4;     // 0..3
    int row0w = bid * 64 + wv * 16;

    float2 xv = ((const float2*)in)[row0w + rsel];

    // layer 0 directly into A fragments (4 K-blocks of 32)
    bf16x8 afr[4];
#pragma unroll
    for (int kb = 0; kb < 4; ++kb) {
#pragma unroll
        for (int j8 = 0; j8 < 8; ++j8) {
            int j = kb * 32 + kgrp * 8 + j8;
            float h = 0.f;
            if (j < 100)
                h = lrelu(fmaf(w0[2*j], xv.x, fmaf(w0[2*j+1], xv.y, b0[j])));
            afr[kb][j8] = (short)f2bf(h);
        }
    }

    // MFMA: 7 N-tiles x 4 K-blocks
    const unsigned short* w1u = (const unsigned short*)w1bf;
    f32x4 acc[7];
#pragma unroll
    for (int n = 0; n < 7; ++n) acc[n] = (f32x4){0.f, 0.f, 0.f, 0.f};
#pragma unroll
    for (int kb = 0; kb < 4; ++kb) {
#pragma unroll
        for (int n = 0; n < 7; ++n) {
            bf16x8 bfr = *(const bf16x8*)(w1u + (n * 16 + rsel) * 128
                                              + kb * 32 + kgrp * 8);
            acc[n] = __builtin_amdgcn_mfma_f32_16x16x32_bf16(afr[kb], bfr,
                                                             acc[n], 0, 0, 0);
        }
    }

    // epilogue: lrelu(+b1) then layer-2 partials, reduce over col lanes
    float py0[4] = {0.f, 0.f, 0.f, 0.f}, py1[4] = {0.f, 0.f, 0.f, 0.f};
#pragma unroll
    for (int n = 0; n < 7; ++n) {
        int i = n * 16 + rsel;
        bool v = (i < 100);
        float b1v = v ? b1[i] : 0.f;
        float w20 = v ? w2[i] : 0.f;
        float w21 = v ? w2[100 + i] : 0.f;
#pragma unroll
        for (int r = 0; r < 4; ++r) {
            float a = lrelu(acc[n][r] + b1v);
            py0[r] = fmaf(a, w20, py0[r]);
            py1[r] = fmaf(a, w21, py1[r]);
        }
    }
#pragma unroll
    for (int r = 0; r < 4; ++r) {
#pragma unroll
        for (int off = 1; off < 16; off <<= 1) {
            py0[r] += __shfl_xor(py0[r], off);
            py1[r] += __shfl_xor(py1[r], off);
        }
    }
    if (rsel == 0) {
#pragma unroll
        for (int r = 0; r < 4; ++r) {
            int row = row0w + kgrp * 4 + r;
            out[row * 2]     = py0[r] + b2[0];
            out[row * 2 + 1] = py1[r] + b2[1];
        }
    }
}

// ---------------------------------------------------------------------------
// K1: merged dispatch: blocks [0,384) = ga GEMM (y1 + mean partials),
// blocks [384, 384+384) = prior table build (4 v-slots per block).
// ---------------------------------------------------------------------------
__global__ __launch_bounds__(256, 2) void k_ga_table(
    const float* __restrict__ in,
    const float* __restrict__ w0, const float* __restrict__ b0,
    const float* __restrict__ w1t,
    const float* __restrict__ b1, const float* __restrict__ w2,
    const float* __restrict__ b2,
    float* __restrict__ out, float* __restrict__ partial,
    const float* __restrict__ eb, const float* __restrict__ u2t,
    float* __restrict__ tbl)
{
    if (blockIdx.x < (unsigned)GA_BLOCKS) {
        gemm2_body<1>(blockIdx.x, in, w0, b0, w1t, b1, w2, b2, out, partial);
    } else {
        int cv4 = blockIdx.x - GA_BLOCKS;      // 0..383
        int c = cv4 >> 4, vg = (cv4 & 15) * 4;
        int m = threadIdx.x;
        float step = (c & 1) ? STEP_ODD : 0.5f;
        float uv = u2t[c * 256 + m];
        const float* P = eb + c * 58;
#pragma unroll
        for (int dv = 0; dv < 4; ++dv) {
            int v = vg + dv;
            float val = (float)(KBASE + v) * step;
            tbl[(c * TBL_CAP + v) * 256 + m] = logpdf_ch(P, val + uv);
        }
    }
}

// ---------------------------------------------------------------------------
// K2: finish the EMA mean from 384 per-block partials (1 block, sub-us)
// ---------------------------------------------------------------------------
__global__ __launch_bounds__(256) void k_mean_final(
    const float* __restrict__ partial, const float* __restrict__ y_mean,
    float* __restrict__ ym)
{
    int tid = threadIdx.x;
    int c = tid >> 3, s = tid & 7;
    float v = 0.f;
    if (c < 24)
        for (int g = s; g < GA_BLOCKS; g += 8) v += partial[g * 24 + c];
    v += __shfl_xor(v, 1); v += __shfl_xor(v, 2); v += __shfl_xor(v, 4);
    if (c < 24 && s == 0)
        ym[c] = fmaf(0.05f, y_mean[c], 0.95f * (v * (1.0f / NB)));
}

// ---------------------------------------------------------------------------
// K3: FUSED coupled transforms. 8 rows/block, 512 blocks.
// Pass A: yhat = hexq(gac(y1-ym)).  Pass B: yhat1 = gsc(yhat) + ym.
// ---------------------------------------------------------------------------
__global__ __launch_bounds__(256, 4) void k_fused24(
    const float* __restrict__ y1,
    const float* __restrict__ w0A, const float* __restrict__ w1tA,
    const float* __restrict__ w2A,
    const float* __restrict__ w0B, const float* __restrict__ w1tB,
    const float* __restrict__ w2B,
    const float* __restrict__ ymg,
    float* __restrict__ yhat, float* __restrict__ yhat1)
{
    __shared__ float sw0[2400];
    __shared__ float sw2[2400];
    __shared__ float sX[8 * 25];
    __shared__ float sO[8 * 25];
    __shared__ alignas(16) float h0[100 * 8];   // [j][r]
    __shared__ float h1[100 * 8];               // [i][r]
    __shared__ float symL[24];

    int tid = threadIdx.x;
    int row0 = blockIdx.x * 8;

    if (tid < 24) symL[tid] = ymg[tid];
    __syncthreads();
    for (int e = tid; e < 192; e += 256) {
        int r = e / 24, c = e - r * 24;
        sX[r * 25 + c] = y1[row0 * 24 + e] - symL[c];
    }

    int ii = tid & 127, rg = tid >> 7;

    for (int pass = 0; pass < 2; ++pass) {
        const float* w0  = pass ? w0B  : w0A;
        const float* w1t = pass ? w1tB : w1tA;
        const float* w2  = pass ? w2B  : w2A;
        for (int t = tid; t < 2400; t += 256) {
            sw0[t] = w0[t];
            sw2[t] = w2[t];
        }
        __syncthreads();

        for (int e = tid; e < 800; e += 256) {
            int j = e >> 3, r = e & 7;
            const float* wr = sw0 + j * 24;
            const float* xr = sX + r * 25;
            float a = 0.f, b = 0.f;
#pragma unroll
            for (int k = 0; k < 24; k += 2) {
                a = fmaf(wr[k],     xr[k],     a);
                b = fmaf(wr[k + 1], xr[k + 1], b);
            }
            h0[j * 8 + r] = splus(a + b);
        }
        __syncthreads();

        {
            float4 a = make_float4(0.f, 0.f, 0.f, 0.f);
            const float* wc = w1t + ii;
            const float4* h4 = (const float4*)h0 + rg;
#pragma unroll 4
            for (int j = 0; j < 100; ++j) {
                float w = wc[j * 128];
                float4 h = h4[j * 2];
                a.x = fmaf(w, h.x, a.x); a.y = fmaf(w, h.y, a.y);
                a.z = fmaf(w, h.z, a.z); a.w = fmaf(w, h.w, a.w);
            }
            if (ii < 100) {
                h1[ii * 8 + rg * 4]     = splus(a.x);
                h1[ii * 8 + rg * 4 + 1] = splus(a.y);
                h1[ii * 8 + rg * 4 + 2] = splus(a.z);
                h1[ii * 8 + rg * 4 + 3] = splus(a.w);
            }
        }
        __syncthreads();

        if (tid < 192) {
            int c = tid >> 3, r = tid & 7;
            const float* w2r = sw2 + c * 100;
            float s = 0.f, s2 = 0.f;
#pragma unroll 4
            for (int i = 0; i < 100; i += 2) {
                s  = fmaf(w2r[i],     h1[i * 8 + r],       s);
                s2 = fmaf(w2r[i + 1], h1[(i + 1) * 8 + r], s2);
            }
            float v = s + s2;
            if (pass == 0) sO[r * 25 + c] = v;
            else yhat1[(row0 + r) * 24 + c] = v + symL[c];
        }

        if (pass == 0) {
            __syncthreads();
            if (tid < 96) {
                int pr = tid >> 3, r = tid & 7;
                float v0 = sO[r * 25 + 2*pr], v1 = sO[r * 25 + 2*pr + 1];
                float q0, q1; hexq(v0, v1, q0, q1);
                yhat[(row0 + r) * 24 + 2*pr]     = q0;
                yhat[(row0 + r) * 24 + 2*pr + 1] = q1;
                sX[r * 25 + 2*pr]     = q0;
                sX[r * 25 + 2*pr + 1] = q1;
            }
        }
    }
}

// ---------------------------------------------------------------------------
// K4 (merged): blocks [0,768) = gs MFMA GEMM -> xhat; blocks [768,768+1024)
// = MC likelihood (4 batch rows/block, unconditional clamped gathers).
// ---------------------------------------------------------------------------
__global__ __launch_bounds__(256, 4) void k_gs_mc(
    const float* __restrict__ yhat1,
    const float* __restrict__ w0, const float* __restrict__ b0,
    const float* __restrict__ w1bf,
    const float* __restrict__ b1, const float* __restrict__ w2,
    const float* __restrict__ b2, float* __restrict__ xhat,
    const float* __restrict__ yhat, const float* __restrict__ u2t,
    const float* __restrict__ eb,
    const float* __restrict__ tbl, float* __restrict__ lik)
{
    if (blockIdx.x < (unsigned)GS_BLOCKS) {
        gs_mfma_body(blockIdx.x, yhat1, w0, b0, w1bf, b1, w2, b2, xhat);
        return;
    }
    __shared__ float sy[4 * 24];
    __shared__ float redm[4], reds[4];
    int tid = threadIdx.x;
    int wv = tid >> 6;
    int bg = (blockIdx.x - GS_BLOCKS) * 4;

    if (tid < 96) sy[tid] = yhat[bg * 24 + tid];
    __syncthreads();

    for (int q = 0; q < 4; ++q) {
        float lp = 0.f;
        unsigned miss = 0;
#pragma unroll
        for (int c = 0; c < 24; ++c) {
            float yv = sy[q * 24 + c];
            float inv = (c & 1) ? INV_ODD : 2.0f;
            int k = (int)rintf(yv * inv);
            int idx = k - KBASE;
            bool ok = (idx >= 0 && idx < TBL_CAP);
            int idq = min(max(idx, 0), TBL_CAP - 1);
            float tv = tbl[(c * TBL_CAP + idq) * 256 + tid];  // unconditional
            lp += ok ? tv : 0.f;
            if (!ok) miss |= (1u << c);
        }
        while (miss) {
            int c = __ffs(miss) - 1;
            miss &= miss - 1;
            lp += logpdf_ch(eb + c * 58, sy[q * 24 + c] + u2t[c * 256 + tid]);
        }

        float m = lp;
#pragma unroll
        for (int off = 1; off < 64; off <<= 1) m = fmaxf(m, __shfl_xor(m, off));
        if ((tid & 63) == 0) redm[wv] = m;
        __syncthreads();
        float mx = fmaxf(fmaxf(redm[0], redm[1]), fmaxf(redm[2], redm[3]));
        float e = __expf(lp - mx);
#pragma unroll
        for (int off = 1; off < 64; off <<= 1) e += __shfl_xor(e, off);
        if ((tid & 63) == 0) reds[wv] = e;
        __syncthreads();
        if (tid == 0)
            lik[bg + q] = mx + __logf(reds[0] + reds[1] + reds[2] + reds[3])
                        - 7.271269879190247f;  // -log(NMC) + LOG_VOL
        __syncthreads();
    }
}

// ---------------------------------------------------------------------------
// Fallback path kernels (ws too small for the table)
// ---------------------------------------------------------------------------
__global__ __launch_bounds__(256, 4) void k_gs(
    const float* __restrict__ yhat1,
    const float* __restrict__ w0, const float* __restrict__ b0,
    const float* __restrict__ w1bf,
    const float* __restrict__ b1, const float* __restrict__ w2,
    const float* __restrict__ b2, float* __restrict__ xhat)
{
    gs_mfma_body(blockIdx.x, yhat1, w0, b0, w1bf, b1, w2, b2, xhat);
}

__global__ __launch_bounds__(256) void k_mc_direct(
    const float* __restrict__ yhat, const float* __restrict__ u2t,
    const float* __restrict__ eb, float* __restrict__ lik)
{
    __shared__ alignas(16) float sU[24 * 256];
    __shared__ float redm[4], reds[4];
    int tid = threadIdx.x;
    int wv = tid >> 6;
    int b = blockIdx.x;
    for (int i = tid; i < 1536; i += 256)
        ((float4*)sU)[i] = ((const float4*)u2t)[i];
    __syncthreads();

    float lp = 0.f;
    for (int c = 0; c < 24; ++c)
        lp += logpdf_ch(eb + c * 58, yhat[b * 24 + c] + sU[c * 256 + tid]);

    float m = lp;
#pragma unroll
    for (int off = 1; off < 64; off <<= 1) m = fmaxf(m, __shfl_xor(m, off));
    if ((tid & 63) == 0) redm[wv] = m;
    __syncthreads();
    float mx = fmaxf(fmaxf(redm[0], redm[1]), fmaxf(redm[2], redm[3]));
    float e = __expf(lp - mx);
#pragma unroll
    for (int off = 1; off < 64; off <<= 1) e += __shfl_xor(e, off);
    if ((tid & 63) == 0) reds[wv] = e;
    __syncthreads();
    if (tid == 0)
        lik[b] = mx + __logf(reds[0] + reds[1] + reds[2] + reds[3])
               - 7.271269879190247f;
}

// ---------------------------------------------------------------------------
extern "C" void kernel_launch(void* const* d_in, const int* in_sizes, int n_in,
                              void* d_out, int out_size, void* d_ws, size_t ws_size,
                              hipStream_t stream)
{
    (void)in_sizes; (void)n_in; (void)out_size;
    const float* x      = (const float*)d_in[0];
    const float* y_mean = (const float*)d_in[1];
    const float* u      = (const float*)d_in[2];
    const float* ga_w0  = (const float*)d_in[3];
    const float* ga_b0  = (const float*)d_in[4];
    const float* ga_w1  = (const float*)d_in[5];
    const float* ga_b1  = (const float*)d_in[6];
    const float* ga_w2  = (const float*)d_in[7];
    const float* ga_b2  = (const float*)d_in[8];
    const float* gs_w0  = (const float*)d_in[9];
    const float* gs_b0  = (const float*)d_in[10];
    const float* gs_w1  = (const float*)d_in[11];
    const float* gs_b1  = (const float*)d_in[12];
    const float* gs_w2  = (const float*)d_in[13];
    const float* gs_b2  = (const float*)d_in[14];
    const float* gac_w0 = (const float*)d_in[15];
    const float* gac_w1 = (const float*)d_in[16];
    const float* gac_w2 = (const float*)d_in[17];
    const float* gsc_w0 = (const float*)d_in[18];
    const float* gsc_w1 = (const float*)d_in[19];
    const float* gsc_w2 = (const float*)d_in[20];
    const float* eb_H0  = (const float*)d_in[21];
    const float* eb_H1  = (const float*)d_in[22];
    const float* eb_H2  = (const float*)d_in[23];
    const float* eb_H3  = (const float*)d_in[24];
    const float* eb_H4  = (const float*)d_in[25];
    const float* eb_b0  = (const float*)d_in[26];
    const float* eb_b1  = (const float*)d_in[27];
    const float* eb_b2  = (const float*)d_in[28];
    const float* eb_b3  = (const float*)d_in[29];
    const float* eb_b4  = (const float*)d_in[30];
    const float* eb_a0  = (const float*)d_in[31];
    const float* eb_a1  = (const float*)d_in[32];
    const float* eb_a2  = (const float*)d_in[33];
    const float* eb_a3  = (const float*)d_in[34];

    float* ws    = (float*)d_ws;
    float* y1    = ws + WS_Y1;
    float* yhat  = ws + WS_YHAT;
    float* yhat1 = ws + WS_YHAT1;
    float* ym    = ws + WS_YM;
    float* u2t   = ws + WS_U2T;
    float* eb    = ws + WS_EB;
    float* part  = ws + WS_PART;
    float* w1t   = ws + WS_W1T;
    float* w1bf  = ws + WS_W1BF;
    float* tbl   = ws + WS_TBL;
    float* xhat  = (float*)d_out;
    float* lik   = (float*)d_out + 98304;

    float* w1tGA  = w1t;
    float* w1tGAC = w1t + 12800;
    float* w1tGSC = w1t + 25600;

    bool use_tbl = ws_size >= WS_END * sizeof(float);

    k_prep<<<207, 256, 0, stream>>>(eb_H0, eb_H1, eb_H2, eb_H3, eb_H4,
                                    eb_b0, eb_b1, eb_b2, eb_b3, eb_b4,
                                    eb_a0, eb_a1, eb_a2, eb_a3, u,
                                    ga_w1, gac_w1, gsc_w1, gs_w1,
                                    eb, u2t, w1t, w1bf);
    if (use_tbl)
        k_ga_table<<<GA_BLOCKS + 24 * TBL_CAP / 4, 256, 0, stream>>>(
            x, ga_w0, ga_b0, w1tGA, ga_b1, ga_w2, ga_b2, y1, part,
            eb, u2t, tbl);
    else
        k_ga_table<<<GA_BLOCKS, 256, 0, stream>>>(
            x, ga_w0, ga_b0, w1tGA, ga_b1, ga_w2, ga_b2, y1, part,
            eb, u2t, tbl);
    k_mean_final<<<1, 256, 0, stream>>>(part, y_mean, ym);
    k_fused24<<<NB / 8, 256, 0, stream>>>(y1, gac_w0, w1tGAC, gac_w2,
                                          gsc_w0, w1tGSC, gsc_w2,
                                          ym, yhat, yhat1);
    if (use_tbl) {
        k_gs_mc<<<GS_BLOCKS + NB / 4, 256, 0, stream>>>(
            yhat1, gs_w0, gs_b0, w1bf, gs_b1, gs_w2, gs_b2, xhat,
            yhat, u2t, eb, tbl, lik);
    } else {
        k_gs<<<GS_BLOCKS, 256, 0, stream>>>(
            yhat1, gs_w0, gs_b0, w1bf, gs_b1, gs_w2, gs_b2, xhat);
        k_mc_direct<<<NB, 256, 0, stream>>>(yhat, u2t, eb, lik);
    }
}